// Round 5
// baseline (289.379 us; speedup 1.0000x reference)
//
#include <hip/hip_runtime.h>
#include <stdint.h>

// ---------------- JAX threefry2x32 (partitionable mode) ----------------
__host__ __device__ inline void tf2x32(uint32_t k0, uint32_t k1,
                                       uint32_t x0, uint32_t x1,
                                       uint32_t& o0, uint32_t& o1) {
  const uint32_t ks2 = k0 ^ k1 ^ 0x1BD11BDAu;
  x0 += k0; x1 += k1;
#define TFR(r) { x0 += x1; x1 = (x1 << (r)) | (x1 >> (32 - (r))); x1 ^= x0; }
  TFR(13) TFR(15) TFR(26) TFR(6)
  x0 += k1;  x1 += ks2 + 1u;
  TFR(17) TFR(29) TFR(16) TFR(24)
  x0 += ks2; x1 += k0 + 2u;
  TFR(13) TFR(15) TFR(26) TFR(6)
  x0 += k0;  x1 += k1 + 3u;
  TFR(17) TFR(29) TFR(16) TFR(24)
  x0 += k1;  x1 += ks2 + 4u;
  TFR(13) TFR(15) TFR(26) TFR(6)
  x0 += ks2; x1 += k0 + 5u;
#undef TFR
  o0 = x0; o1 = x1;
}

__host__ __device__ inline uint32_t bits32(uint32_t k0, uint32_t k1, uint32_t idx) {
  uint32_t a, b;
  tf2x32(k0, k1, 0u, idx, a, b);
  return a ^ b;
}

// keep-edge iff uniform >= 0.5 iff bit31 of bits set (floor(0.5+u) == 1)
__device__ inline bool edge_kept(uint32_t k0, uint32_t k1, uint32_t e) {
  return (bits32(k0, k1, e) >> 31) != 0u;
}

__device__ inline float bf_lo(uint32_t u) { return __uint_as_float(u << 16); }
__device__ inline float bf_hi(uint32_t u) { return __uint_as_float(u & 0xffff0000u); }
__device__ inline uint32_t bf_pack(float a, float b) {
  uint32_t lo = (__float_as_uint(a) + 0x8000u) >> 16;
  uint32_t hi = (__float_as_uint(b) + 0x8000u) & 0xffff0000u;
  return hi | lo;
}

__device__ inline void fma8_f32(float a[8], float v, const float4& x0, const float4& x1) {
  a[0] = fmaf(v, x0.x, a[0]); a[1] = fmaf(v, x0.y, a[1]);
  a[2] = fmaf(v, x0.z, a[2]); a[3] = fmaf(v, x0.w, a[3]);
  a[4] = fmaf(v, x1.x, a[4]); a[5] = fmaf(v, x1.y, a[5]);
  a[6] = fmaf(v, x1.z, a[6]); a[7] = fmaf(v, x1.w, a[7]);
}
__device__ inline void fma8_bf(float a[8], float v, const uint4& u) {
  a[0] = fmaf(v, bf_lo(u.x), a[0]); a[1] = fmaf(v, bf_hi(u.x), a[1]);
  a[2] = fmaf(v, bf_lo(u.y), a[2]); a[3] = fmaf(v, bf_hi(u.y), a[3]);
  a[4] = fmaf(v, bf_lo(u.z), a[4]); a[5] = fmaf(v, bf_hi(u.z), a[5]);
  a[6] = fmaf(v, bf_lo(u.w), a[6]); a[7] = fmaf(v, bf_hi(u.w), a[7]);
}

// ---------------- CSR build ----------------
__global__ void k_count(const int* __restrict__ rows, int nnz, int* __restrict__ cnt,
                        uint32_t ke0, uint32_t ke1) {
  int e = blockIdx.x * 256 + threadIdx.x;
  if (e >= nnz) return;
  if (edge_kept(ke0, ke1, (uint32_t)e)) atomicAdd(&cnt[rows[e]], 1);
}

__global__ void k_blocksum(const int* __restrict__ cnt, int n, int* __restrict__ bsum) {
  __shared__ int s[256];
  int i = blockIdx.x * 256 + threadIdx.x;
  s[threadIdx.x] = (i < n) ? cnt[i] : 0;
  __syncthreads();
  for (int off = 128; off > 0; off >>= 1) {
    if (threadIdx.x < off) s[threadIdx.x] += s[threadIdx.x + off];
    __syncthreads();
  }
  if (threadIdx.x == 0) bsum[blockIdx.x] = s[0];
}

// single block, 1024 threads, scans up to 2048 block sums -> exclusive prefix
__global__ void k_scanb(const int* __restrict__ bsum, int nb, int* __restrict__ bpref) {
  __shared__ int a[2048], b[2048];
  int t = threadIdx.x;
  for (int i = t; i < 2048; i += 1024) a[i] = (i < nb) ? bsum[i] : 0;
  __syncthreads();
  int* cur = a; int* nxt = b;
  for (int off = 1; off < 2048; off <<= 1) {
    for (int i = t; i < 2048; i += 1024)
      nxt[i] = cur[i] + (i >= off ? cur[i - off] : 0);
    __syncthreads();
    int* tmp = cur; cur = nxt; nxt = tmp;
  }
  for (int i = t; i <= nb; i += 1024)
    bpref[i] = (i == 0) ? 0 : cur[i - 1];
}

__global__ void k_scan_write(const int* __restrict__ cnt, int n, const int* __restrict__ bpref,
                             int* __restrict__ row_ptr, int* __restrict__ nextc) {
  __shared__ int a[256], b[256];
  int t = threadIdx.x;
  int i = blockIdx.x * 256 + t;
  int v = (i < n) ? cnt[i] : 0;
  a[t] = v;
  __syncthreads();
  int* cur = a; int* nxt = b;
  for (int off = 1; off < 256; off <<= 1) {
    nxt[t] = cur[t] + (t >= off ? cur[t - off] : 0);
    __syncthreads();
    int* tmp = cur; cur = nxt; nxt = tmp;
  }
  int incl = cur[t] + bpref[blockIdx.x];
  int excl = incl - v;
  if (i < n) { row_ptr[i] = excl; nextc[i] = excl; }
  if (i == n - 1) row_ptr[n] = incl;
}

__global__ void k_scatter(const float* __restrict__ avals, const int* __restrict__ rows,
                          const int* __restrict__ cols, int nnz, int* __restrict__ nextc,
                          int2* __restrict__ slot, uint32_t ke0, uint32_t ke1) {
  int e = blockIdx.x * 256 + threadIdx.x;
  if (e >= nnz) return;
  if (!edge_kept(ke0, ke1, (uint32_t)e)) return;
  int r = rows[e];
  int k = atomicAdd(&nextc[r], 1);
  slot[k] = make_int2(cols[e], __float_as_int(avals[e] * 2.0f)); // *keep*1/(1-0.5)
}

// ---------------- frontier marking + compaction ----------------
__global__ void k_mark_batch(const int* __restrict__ users, const int* __restrict__ items,
                             int batch, int nu, uint8_t* fB, uint8_t* f1, uint8_t* f2) {
  int i = blockIdx.x * 256 + threadIdx.x;
  if (i >= 2 * batch) return;
  int r = (i < batch) ? users[i] : nu + items[i - batch];
  fB[r] = 1; f1[r] = 1; f2[r] = 1;
}

__global__ void k_mark_neighbors(const uint8_t* __restrict__ fin,
                                 const int* __restrict__ row_ptr,
                                 const int2* __restrict__ slot, int n,
                                 uint8_t* __restrict__ fout) {
  int r = blockIdx.x * 256 + threadIdx.x;
  if (r >= n) return;
  if (!fin[r]) return;
  int s = row_ptr[r], e = row_ptr[r + 1];
  for (int k = s; k < e; ++k) fout[slot[k].x] = 1;
}

// dense list of flagged rows; wave-aggregated single-counter atomic:
// one atomicAdd per wave (leader), per-lane offsets from the ballot mask.
__global__ void k_compact(const uint8_t* __restrict__ flag, int n,
                          int* __restrict__ list, int* __restrict__ cnt) {
  int r = blockIdx.x * 256 + threadIdx.x;
  int lane = threadIdx.x & 63;
  bool f = (r < n) && flag[r];
  unsigned long long mask = __ballot(f);
  if (mask == 0ull) return;
  int leader = __ffsll((long long)mask) - 1;
  int base = 0;
  if (lane == leader) base = atomicAdd(cnt, __popcll(mask));
  base = __shfl(base, leader, 64);
  if (f) {
    int off = __popcll(mask & ((lane == 63) ? ~0ull >> 1 : ((1ull << lane) - 1ull)));
    // note: (1ull<<63)-1 is fine too; branch avoids UB paranoia only
    list[base + off] = r;
  }
}

// -------- SPMM: 8 lanes per row (lane owns 8 dims), 8 rows per wave --------
// X buffers are bf16x2-packed (uint32, 32 words per row).
template <int FIRST>
__global__ __launch_bounds__(256) void k_spmm(
    const int* __restrict__ row_ptr, const int2* __restrict__ slot,
    const uint32_t* __restrict__ xin, const float* __restrict__ uemb,
    const float* __restrict__ iemb, uint32_t* __restrict__ xout,
    const int* __restrict__ rowlist, const int* __restrict__ nrows_p, int nu) {
  int nrows = *nrows_p;
  int i = blockIdx.x * 32 + (threadIdx.x >> 3);
  if (i >= nrows) return;
  int r = rowlist[i];
  int j = threadIdx.x & 7;
  int s = row_ptr[r], e = row_ptr[r + 1];
  float a[8] = {0, 0, 0, 0, 0, 0, 0, 0};
  for (int k = s; k < e; k += 2) {
    int2 s0 = slot[k];
    bool has1 = (k + 1 < e);
    int2 s1 = slot[has1 ? k + 1 : k];
    float v0 = __int_as_float(s0.y);
    float v1 = has1 ? __int_as_float(s1.y) : 0.0f;
    if (FIRST) {
      const float* p0 = (s0.x < nu) ? uemb + (size_t)s0.x * 64
                                    : iemb + (size_t)(s0.x - nu) * 64;
      const float* p1 = (s1.x < nu) ? uemb + (size_t)s1.x * 64
                                    : iemb + (size_t)(s1.x - nu) * 64;
      float4 xa0 = *(const float4*)(p0 + 8 * j);
      float4 xb0 = *(const float4*)(p0 + 8 * j + 4);
      float4 xa1 = *(const float4*)(p1 + 8 * j);
      float4 xb1 = *(const float4*)(p1 + 8 * j + 4);
      fma8_f32(a, v0, xa0, xb0);
      fma8_f32(a, v1, xa1, xb1);
    } else {
      uint4 u0 = *(const uint4*)(xin + (size_t)s0.x * 32 + 4 * j);
      uint4 u1 = *(const uint4*)(xin + (size_t)s1.x * 32 + 4 * j);
      fma8_bf(a, v0, u0);
      fma8_bf(a, v1, u1);
    }
  }
  uint4 o;
  o.x = bf_pack(a[0], a[1]); o.y = bf_pack(a[2], a[3]);
  o.z = bf_pack(a[4], a[5]); o.w = bf_pack(a[6], a[7]);
  *(uint4*)(xout + (size_t)r * 32 + 4 * j) = o;
}

// ---- layer-3 SPMM fused into the batch gather: only 2B rows needed ----
__global__ __launch_bounds__(256) void k_spmm_gather(
    const int* __restrict__ row_ptr, const int2* __restrict__ slot,
    const uint32_t* __restrict__ xin, const int* __restrict__ users,
    const int* __restrict__ items, float* __restrict__ out,
    int batch, int nu) {
  int b = blockIdx.x * 32 + (threadIdx.x >> 3);
  if (b >= 2 * batch) return;
  int j = threadIdx.x & 7;
  size_t H = (size_t)batch * 64;
  int r; size_t dst;
  if (b < batch) {
    r = users[b];
    dst = (size_t)b * 64;
  } else {
    int bi = b - batch;
    r = nu + items[bi];
    dst = 2 * H + (size_t)bi * 64;
  }
  int s = row_ptr[r], e = row_ptr[r + 1];
  float a[8] = {0, 0, 0, 0, 0, 0, 0, 0};
  for (int k = s; k < e; k += 2) {
    int2 s0 = slot[k];
    bool has1 = (k + 1 < e);
    int2 s1 = slot[has1 ? k + 1 : k];
    float v0 = __int_as_float(s0.y);
    float v1 = has1 ? __int_as_float(s1.y) : 0.0f;
    uint4 u0 = *(const uint4*)(xin + (size_t)s0.x * 32 + 4 * j);
    uint4 u1 = *(const uint4*)(xin + (size_t)s1.x * 32 + 4 * j);
    fma8_bf(a, v0, u0);
    fma8_bf(a, v1, u1);
  }
  float* o = out + dst + 8 * j;
  float4 t0 = *(float4*)o;
  float4 t1 = *(float4*)(o + 4);
  t0.x += a[0]; t0.y += a[1]; t0.z += a[2]; t0.w += a[3];
  t1.x += a[4]; t1.y += a[5]; t1.z += a[6]; t1.w += a[7];
  *(float4*)o = t0;
  *(float4*)(o + 4) = t1;
}

// ---------------- batch gather, accumulated into d_out ----------------
// out layout: [u_online | u_target | i_online | i_target], H = B*64 each.
template <int INIT>
__global__ void k_gather(const uint32_t* __restrict__ x, const float* __restrict__ uemb,
                         const float* __restrict__ iemb, const int* __restrict__ users,
                         const int* __restrict__ items, float* __restrict__ out,
                         int batch, int nu) {
  int b = blockIdx.x * 32 + (threadIdx.x >> 3);
  if (b >= 2 * batch) return;
  int j = threadIdx.x & 7;
  size_t H = (size_t)batch * 64;
  int row; size_t dst; bool isu = b < batch;
  if (isu) {
    row = users[b];
    dst = (size_t)b * 64 + 8 * j;
  } else {
    int bi = b - batch;
    row = items[bi];
    dst = 2 * H + (size_t)bi * 64 + 8 * j;
  }
  if (INIT) {
    const float* p = (isu ? uemb + (size_t)row * 64 : iemb + (size_t)row * 64) + 8 * j;
    *(float4*)(out + dst) = *(const float4*)p;
    *(float4*)(out + dst + 4) = *(const float4*)(p + 4);
  } else {
    int xr = isu ? row : nu + row;
    uint4 u = *(const uint4*)(x + (size_t)xr * 32 + 4 * j);
    float* o = out + dst;
    float4 t0 = *(float4*)o;
    float4 t1 = *(float4*)(o + 4);
    t0.x += bf_lo(u.x); t0.y += bf_hi(u.x); t0.z += bf_lo(u.y); t0.w += bf_hi(u.y);
    t1.x += bf_lo(u.z); t1.y += bf_hi(u.z); t1.z += bf_lo(u.w); t1.w += bf_hi(u.w);
    *(float4*)o = t0;
    *(float4*)(o + 4) = t1;
  }
}

// ---------------- finalize: /4, target dropout masks ----------------
__global__ void k_finalize(float* __restrict__ out, int batch,
                           uint32_t ku0, uint32_t ku1, uint32_t ki0, uint32_t ki1) {
  int j = blockIdx.x * 256 + threadIdx.x;
  int H = batch * 64;
  if (j >= 2 * H) return;
  bool is_u = j < H;
  int f = is_u ? j : j - H;
  size_t online = is_u ? (size_t)f : (size_t)2 * H + f;
  uint32_t k0 = is_u ? ku0 : ki0;
  uint32_t k1 = is_u ? ku1 : ki1;
  float o = out[online] * 0.25f;                       // acc / (N_LAYERS+1), exact
  bool present = (bits32(k0, k1, (uint32_t)f) >> 31) == 0u;  // bernoulli(0.5)
  out[online] = o;
  out[online + H] = present ? o * 2.0f : 0.0f;         // t / (1-0.5), exact
}

extern "C" void kernel_launch(void* const* d_in, const int* in_sizes, int n_in,
                              void* d_out, int out_size, void* d_ws, size_t ws_size,
                              hipStream_t stream) {
  const float* uemb  = (const float*)d_in[0];
  const float* iemb  = (const float*)d_in[1];
  const float* avals = (const float*)d_in[2];
  const int*   rows  = (const int*)d_in[3];
  const int*   cols  = (const int*)d_in[4];
  const int*   users = (const int*)d_in[5];
  const int*   items = (const int*)d_in[6];
  const int DIM = 64;
  const int NU = in_sizes[0] / DIM;
  const int NI = in_sizes[1] / DIM;
  const int NNZ = in_sizes[2];
  const int B = in_sizes[5];
  const int NN = NU + NI;
  float* out = (float*)d_out;
  (void)n_in; (void)out_size; (void)ws_size;

  // derived subkeys: split(key(1234), 3) fold-like = threefry(key, (0, i))
  uint32_t ke0, ke1, ku0, ku1, ki0, ki1;
  tf2x32(0u, 1234u, 0u, 0u, ke0, ke1);
  tf2x32(0u, 1234u, 0u, 1u, ku0, ku1);
  tf2x32(0u, 1234u, 0u, 2u, ki0, ki1);

  // workspace carve
  char* p = (char*)d_ws;
  auto carve = [&](size_t bytes) {
    char* r = p;
    p += (bytes + 255) & ~(size_t)255;
    return (void*)r;
  };
  uint32_t* X0    = (uint32_t*)carve((size_t)NN * 32 * 4);  // bf16x2 rows
  uint32_t* X1    = (uint32_t*)carve((size_t)NN * 32 * 4);
  int2*  slot     = (int2*)carve((size_t)NNZ * 8);
  int*   cnt      = (int*)carve((size_t)NN * 4);
  int*   row_ptr  = (int*)carve((size_t)(NN + 1) * 4);
  int*   nextc    = (int*)carve((size_t)NN * 4);
  uint8_t* fB     = (uint8_t*)carve((size_t)NN * 3);  // fB | f1 | f2
  uint8_t* f1     = fB + NN;
  uint8_t* f2     = fB + 2 * (size_t)NN;
  int*   list1    = (int*)carve((size_t)NN * 4);
  int*   list2    = (int*)carve((size_t)NN * 4);
  int*   rcnt     = (int*)carve(8);                   // [0]=|f1|, [1]=|f2|
  const int NB    = (NN + 255) / 256;
  int*   bsum     = (int*)carve((size_t)NB * 4);
  int*   bpref    = (int*)carve((size_t)(NB + 1) * 4);

  hipMemsetAsync(cnt, 0, (size_t)NN * 4, stream);
  hipMemsetAsync(fB, 0, (size_t)NN * 3, stream);
  hipMemsetAsync(rcnt, 0, 8, stream);

  const int gE = (NNZ + 255) / 256;
  const int gN = (NN + 255) / 256;
  k_count<<<gE, 256, 0, stream>>>(rows, NNZ, cnt, ke0, ke1);
  k_blocksum<<<NB, 256, 0, stream>>>(cnt, NN, bsum);
  k_scanb<<<1, 1024, 0, stream>>>(bsum, NB, bpref);
  k_scan_write<<<NB, 256, 0, stream>>>(cnt, NN, bpref, row_ptr, nextc);
  k_scatter<<<gE, 256, 0, stream>>>(avals, rows, cols, NNZ, nextc, slot, ke0, ke1);

  // frontier: f2 = batch ∪ N(batch); f1 = batch ∪ N(f2); compact to lists
  const int gB = (2 * B + 255) / 256;
  k_mark_batch<<<gB, 256, 0, stream>>>(users, items, B, NU, fB, f1, f2);
  k_mark_neighbors<<<gN, 256, 0, stream>>>(fB, row_ptr, slot, NN, f2);
  k_mark_neighbors<<<gN, 256, 0, stream>>>(f2, row_ptr, slot, NN, f1);
  k_compact<<<gN, 256, 0, stream>>>(f1, NN, list1, rcnt);
  k_compact<<<gN, 256, 0, stream>>>(f2, NN, list2, rcnt + 1);

  const int gG = (2 * B + 31) / 32;   // 32 rows/block (8 lanes per row)
  const int gS = (NN + 31) / 32;      // upper bound; spmm exits past rcnt

  // layer-0 contribution (the raw embeddings) into online slots
  k_gather<1><<<gG, 256, 0, stream>>>(X0, uemb, iemb, users, items, out, B, NU);

  // layer 1: X0 = A * emb (rows in list1), accumulate batch rows
  k_spmm<1><<<gS, 256, 0, stream>>>(row_ptr, slot, X1, uemb, iemb, X0, list1, rcnt, NU);
  k_gather<0><<<gG, 256, 0, stream>>>(X0, uemb, iemb, users, items, out, B, NU);
  // layer 2: X1 = A * X0 (rows in list2), accumulate batch rows
  k_spmm<0><<<gS, 256, 0, stream>>>(row_ptr, slot, X0, uemb, iemb, X1, list2, rcnt + 1, NU);
  k_gather<0><<<gG, 256, 0, stream>>>(X1, uemb, iemb, users, items, out, B, NU);
  // layer 3: only the 2B gathered rows are ever read -> fuse into gather
  k_spmm_gather<<<gG, 256, 0, stream>>>(row_ptr, slot, X1, users, items, out, B, NU);

  const int gF = (2 * B * DIM + 255) / 256;
  k_finalize<<<gF, 256, 0, stream>>>(out, B, ku0, ku1, ki0, ki1);
}

// Round 6
// 189.451 us; speedup vs baseline: 1.5275x; 1.5275x over previous
//
#include <hip/hip_runtime.h>
#include <stdint.h>

// ---------------- JAX threefry2x32 (partitionable mode) ----------------
__host__ __device__ inline void tf2x32(uint32_t k0, uint32_t k1,
                                       uint32_t x0, uint32_t x1,
                                       uint32_t& o0, uint32_t& o1) {
  const uint32_t ks2 = k0 ^ k1 ^ 0x1BD11BDAu;
  x0 += k0; x1 += k1;
#define TFR(r) { x0 += x1; x1 = (x1 << (r)) | (x1 >> (32 - (r))); x1 ^= x0; }
  TFR(13) TFR(15) TFR(26) TFR(6)
  x0 += k1;  x1 += ks2 + 1u;
  TFR(17) TFR(29) TFR(16) TFR(24)
  x0 += ks2; x1 += k0 + 2u;
  TFR(13) TFR(15) TFR(26) TFR(6)
  x0 += k0;  x1 += k1 + 3u;
  TFR(17) TFR(29) TFR(16) TFR(24)
  x0 += k1;  x1 += ks2 + 4u;
  TFR(13) TFR(15) TFR(26) TFR(6)
  x0 += ks2; x1 += k0 + 5u;
#undef TFR
  o0 = x0; o1 = x1;
}

__host__ __device__ inline uint32_t bits32(uint32_t k0, uint32_t k1, uint32_t idx) {
  uint32_t a, b;
  tf2x32(k0, k1, 0u, idx, a, b);
  return a ^ b;
}

// keep-edge iff uniform >= 0.5 iff bit31 of bits set (floor(0.5+u) == 1)
__device__ inline bool edge_kept(uint32_t k0, uint32_t k1, uint32_t e) {
  return (bits32(k0, k1, e) >> 31) != 0u;
}

__device__ inline float bf_lo(uint32_t u) { return __uint_as_float(u << 16); }
__device__ inline float bf_hi(uint32_t u) { return __uint_as_float(u & 0xffff0000u); }
__device__ inline uint32_t bf_pack(float a, float b) {
  uint32_t lo = (__float_as_uint(a) + 0x8000u) >> 16;
  uint32_t hi = (__float_as_uint(b) + 0x8000u) & 0xffff0000u;
  return hi | lo;
}

__device__ inline void fma8_f32(float a[8], float v, const float4& x0, const float4& x1) {
  a[0] = fmaf(v, x0.x, a[0]); a[1] = fmaf(v, x0.y, a[1]);
  a[2] = fmaf(v, x0.z, a[2]); a[3] = fmaf(v, x0.w, a[3]);
  a[4] = fmaf(v, x1.x, a[4]); a[5] = fmaf(v, x1.y, a[5]);
  a[6] = fmaf(v, x1.z, a[6]); a[7] = fmaf(v, x1.w, a[7]);
}
__device__ inline void fma8_bf(float a[8], float v, const uint4& u) {
  a[0] = fmaf(v, bf_lo(u.x), a[0]); a[1] = fmaf(v, bf_hi(u.x), a[1]);
  a[2] = fmaf(v, bf_lo(u.y), a[2]); a[3] = fmaf(v, bf_hi(u.y), a[3]);
  a[4] = fmaf(v, bf_lo(u.z), a[4]); a[5] = fmaf(v, bf_hi(u.z), a[5]);
  a[6] = fmaf(v, bf_lo(u.w), a[6]); a[7] = fmaf(v, bf_hi(u.w), a[7]);
}

// ---------------- CSR build ----------------
__global__ void k_count(const int* __restrict__ rows, int nnz, int* __restrict__ cnt,
                        uint32_t ke0, uint32_t ke1) {
  int e = blockIdx.x * 256 + threadIdx.x;
  if (e >= nnz) return;
  if (edge_kept(ke0, ke1, (uint32_t)e)) atomicAdd(&cnt[rows[e]], 1);
}

__global__ void k_blocksum(const int* __restrict__ cnt, int n, int* __restrict__ bsum) {
  __shared__ int s[256];
  int i = blockIdx.x * 256 + threadIdx.x;
  s[threadIdx.x] = (i < n) ? cnt[i] : 0;
  __syncthreads();
  for (int off = 128; off > 0; off >>= 1) {
    if (threadIdx.x < off) s[threadIdx.x] += s[threadIdx.x + off];
    __syncthreads();
  }
  if (threadIdx.x == 0) bsum[blockIdx.x] = s[0];
}

// single block, 1024 threads, scans up to 2048 block sums -> exclusive prefix
// (bpref[0]=0, bpref[nb]=total)
__device__ inline void scan_block_1024(const int* __restrict__ bsum, int nb,
                                       int* __restrict__ bpref,
                                       int* a, int* b) {
  int t = threadIdx.x;
  for (int i = t; i < 2048; i += 1024) a[i] = (i < nb) ? bsum[i] : 0;
  __syncthreads();
  int* cur = a; int* nxt = b;
  for (int off = 1; off < 2048; off <<= 1) {
    for (int i = t; i < 2048; i += 1024)
      nxt[i] = cur[i] + (i >= off ? cur[i - off] : 0);
    __syncthreads();
    int* tmp = cur; cur = nxt; nxt = tmp;
  }
  for (int i = t; i <= nb; i += 1024)
    bpref[i] = (i == 0) ? 0 : cur[i - 1];
  __syncthreads();
}

__global__ void k_scanb(const int* __restrict__ bsum, int nb, int* __restrict__ bpref) {
  __shared__ int a[2048], b[2048];
  scan_block_1024(bsum, nb, bpref, a, b);
}

__global__ void k_scan_write(const int* __restrict__ cnt, int n, const int* __restrict__ bpref,
                             int* __restrict__ row_ptr, int* __restrict__ nextc) {
  __shared__ int a[256], b[256];
  int t = threadIdx.x;
  int i = blockIdx.x * 256 + t;
  int v = (i < n) ? cnt[i] : 0;
  a[t] = v;
  __syncthreads();
  int* cur = a; int* nxt = b;
  for (int off = 1; off < 256; off <<= 1) {
    nxt[t] = cur[t] + (t >= off ? cur[t - off] : 0);
    __syncthreads();
    int* tmp = cur; cur = nxt; nxt = tmp;
  }
  int incl = cur[t] + bpref[blockIdx.x];
  int excl = incl - v;
  if (i < n) { row_ptr[i] = excl; nextc[i] = excl; }
  if (i == n - 1) row_ptr[n] = incl;
}

__global__ void k_scatter(const float* __restrict__ avals, const int* __restrict__ rows,
                          const int* __restrict__ cols, int nnz, int* __restrict__ nextc,
                          int2* __restrict__ slot, uint32_t ke0, uint32_t ke1) {
  int e = blockIdx.x * 256 + threadIdx.x;
  if (e >= nnz) return;
  if (!edge_kept(ke0, ke1, (uint32_t)e)) return;
  int r = rows[e];
  int k = atomicAdd(&nextc[r], 1);
  slot[k] = make_int2(cols[e], __float_as_int(avals[e] * 2.0f)); // *keep*1/(1-0.5)
}

// ---------------- frontier marking + scan-based compaction ----------------
__global__ void k_mark_batch(const int* __restrict__ users, const int* __restrict__ items,
                             int batch, int nu, uint8_t* fB, uint8_t* f1, uint8_t* f2) {
  int i = blockIdx.x * 256 + threadIdx.x;
  if (i >= 2 * batch) return;
  int r = (i < batch) ? users[i] : nu + items[i - batch];
  fB[r] = 1; f1[r] = 1; f2[r] = 1;
}

__global__ void k_mark_neighbors(const uint8_t* __restrict__ fin,
                                 const int* __restrict__ row_ptr,
                                 const int2* __restrict__ slot, int n,
                                 uint8_t* __restrict__ fout) {
  int r = blockIdx.x * 256 + threadIdx.x;
  if (r >= n) return;
  if (!fin[r]) return;
  int s = row_ptr[r], e = row_ptr[r + 1];
  for (int k = s; k < e; ++k) fout[slot[k].x] = 1;
}

// per-block sums of both flag arrays in one pass
__global__ void k_flagsum2(const uint8_t* __restrict__ f1, const uint8_t* __restrict__ f2,
                           int n, int* __restrict__ bsum1, int* __restrict__ bsum2) {
  __shared__ int s1[256], s2[256];
  int i = blockIdx.x * 256 + threadIdx.x;
  s1[threadIdx.x] = (i < n) ? (int)f1[i] : 0;
  s2[threadIdx.x] = (i < n) ? (int)f2[i] : 0;
  __syncthreads();
  for (int off = 128; off > 0; off >>= 1) {
    if (threadIdx.x < off) {
      s1[threadIdx.x] += s1[threadIdx.x + off];
      s2[threadIdx.x] += s2[threadIdx.x + off];
    }
    __syncthreads();
  }
  if (threadIdx.x == 0) { bsum1[blockIdx.x] = s1[0]; bsum2[blockIdx.x] = s2[0]; }
}

// scan both block-sum arrays in one single-block kernel
__global__ void k_scanb2(const int* __restrict__ bsum1, const int* __restrict__ bsum2,
                         int nb, int* __restrict__ bpref1, int* __restrict__ bpref2) {
  __shared__ int a[2048], b[2048];
  scan_block_1024(bsum1, nb, bpref1, a, b);
  scan_block_1024(bsum2, nb, bpref2, a, b);
}

// write both lists: LDS local prefix + per-block base; no global atomics.
__global__ void k_compact2(const uint8_t* __restrict__ f1, const uint8_t* __restrict__ f2,
                           int n, const int* __restrict__ bpref1,
                           const int* __restrict__ bpref2,
                           int* __restrict__ list1, int* __restrict__ list2) {
  __shared__ int a[256], b[256];
  int t = threadIdx.x;
  int i = blockIdx.x * 256 + t;

  // f1
  int v = (i < n) ? (int)f1[i] : 0;
  a[t] = v;
  __syncthreads();
  int* cur = a; int* nxt = b;
  for (int off = 1; off < 256; off <<= 1) {
    nxt[t] = cur[t] + (t >= off ? cur[t - off] : 0);
    __syncthreads();
    int* tmp = cur; cur = nxt; nxt = tmp;
  }
  if (v) list1[bpref1[blockIdx.x] + cur[t] - 1] = i;
  __syncthreads();

  // f2
  v = (i < n) ? (int)f2[i] : 0;
  a[t] = v;
  __syncthreads();
  cur = a; nxt = b;
  for (int off = 1; off < 256; off <<= 1) {
    nxt[t] = cur[t] + (t >= off ? cur[t - off] : 0);
    __syncthreads();
    int* tmp = cur; cur = nxt; nxt = tmp;
  }
  if (v) list2[bpref2[blockIdx.x] + cur[t] - 1] = i;
}

// -------- SPMM: 8 lanes per row (lane owns 8 dims), 8 rows per wave --------
// X buffers are bf16x2-packed (uint32, 32 words per row).
template <int FIRST>
__global__ __launch_bounds__(256) void k_spmm(
    const int* __restrict__ row_ptr, const int2* __restrict__ slot,
    const uint32_t* __restrict__ xin, const float* __restrict__ uemb,
    const float* __restrict__ iemb, uint32_t* __restrict__ xout,
    const int* __restrict__ rowlist, const int* __restrict__ nrows_p, int nu) {
  int nrows = *nrows_p;
  int i = blockIdx.x * 32 + (threadIdx.x >> 3);
  if (i >= nrows) return;
  int r = rowlist[i];
  int j = threadIdx.x & 7;
  int s = row_ptr[r], e = row_ptr[r + 1];
  float a[8] = {0, 0, 0, 0, 0, 0, 0, 0};
  for (int k = s; k < e; k += 2) {
    int2 s0 = slot[k];
    bool has1 = (k + 1 < e);
    int2 s1 = slot[has1 ? k + 1 : k];
    float v0 = __int_as_float(s0.y);
    float v1 = has1 ? __int_as_float(s1.y) : 0.0f;
    if (FIRST) {
      const float* p0 = (s0.x < nu) ? uemb + (size_t)s0.x * 64
                                    : iemb + (size_t)(s0.x - nu) * 64;
      const float* p1 = (s1.x < nu) ? uemb + (size_t)s1.x * 64
                                    : iemb + (size_t)(s1.x - nu) * 64;
      float4 xa0 = *(const float4*)(p0 + 8 * j);
      float4 xb0 = *(const float4*)(p0 + 8 * j + 4);
      float4 xa1 = *(const float4*)(p1 + 8 * j);
      float4 xb1 = *(const float4*)(p1 + 8 * j + 4);
      fma8_f32(a, v0, xa0, xb0);
      fma8_f32(a, v1, xa1, xb1);
    } else {
      uint4 u0 = *(const uint4*)(xin + (size_t)s0.x * 32 + 4 * j);
      uint4 u1 = *(const uint4*)(xin + (size_t)s1.x * 32 + 4 * j);
      fma8_bf(a, v0, u0);
      fma8_bf(a, v1, u1);
    }
  }
  uint4 o;
  o.x = bf_pack(a[0], a[1]); o.y = bf_pack(a[2], a[3]);
  o.z = bf_pack(a[4], a[5]); o.w = bf_pack(a[6], a[7]);
  *(uint4*)(xout + (size_t)r * 32 + 4 * j) = o;
}

// ---- layer-3 SPMM fused into the batch gather: only 2B rows needed ----
__global__ __launch_bounds__(256) void k_spmm_gather(
    const int* __restrict__ row_ptr, const int2* __restrict__ slot,
    const uint32_t* __restrict__ xin, const int* __restrict__ users,
    const int* __restrict__ items, float* __restrict__ out,
    int batch, int nu) {
  int b = blockIdx.x * 32 + (threadIdx.x >> 3);
  if (b >= 2 * batch) return;
  int j = threadIdx.x & 7;
  size_t H = (size_t)batch * 64;
  int r; size_t dst;
  if (b < batch) {
    r = users[b];
    dst = (size_t)b * 64;
  } else {
    int bi = b - batch;
    r = nu + items[bi];
    dst = 2 * H + (size_t)bi * 64;
  }
  int s = row_ptr[r], e = row_ptr[r + 1];
  float a[8] = {0, 0, 0, 0, 0, 0, 0, 0};
  for (int k = s; k < e; k += 2) {
    int2 s0 = slot[k];
    bool has1 = (k + 1 < e);
    int2 s1 = slot[has1 ? k + 1 : k];
    float v0 = __int_as_float(s0.y);
    float v1 = has1 ? __int_as_float(s1.y) : 0.0f;
    uint4 u0 = *(const uint4*)(xin + (size_t)s0.x * 32 + 4 * j);
    uint4 u1 = *(const uint4*)(xin + (size_t)s1.x * 32 + 4 * j);
    fma8_bf(a, v0, u0);
    fma8_bf(a, v1, u1);
  }
  float* o = out + dst + 8 * j;
  float4 t0 = *(float4*)o;
  float4 t1 = *(float4*)(o + 4);
  t0.x += a[0]; t0.y += a[1]; t0.z += a[2]; t0.w += a[3];
  t1.x += a[4]; t1.y += a[5]; t1.z += a[6]; t1.w += a[7];
  *(float4*)o = t0;
  *(float4*)(o + 4) = t1;
}

// ---------------- batch gather, accumulated into d_out ----------------
// out layout: [u_online | u_target | i_online | i_target], H = B*64 each.
template <int INIT>
__global__ void k_gather(const uint32_t* __restrict__ x, const float* __restrict__ uemb,
                         const float* __restrict__ iemb, const int* __restrict__ users,
                         const int* __restrict__ items, float* __restrict__ out,
                         int batch, int nu) {
  int b = blockIdx.x * 32 + (threadIdx.x >> 3);
  if (b >= 2 * batch) return;
  int j = threadIdx.x & 7;
  size_t H = (size_t)batch * 64;
  int row; size_t dst; bool isu = b < batch;
  if (isu) {
    row = users[b];
    dst = (size_t)b * 64 + 8 * j;
  } else {
    int bi = b - batch;
    row = items[bi];
    dst = 2 * H + (size_t)bi * 64 + 8 * j;
  }
  if (INIT) {
    const float* p = (isu ? uemb + (size_t)row * 64 : iemb + (size_t)row * 64) + 8 * j;
    *(float4*)(out + dst) = *(const float4*)p;
    *(float4*)(out + dst + 4) = *(const float4*)(p + 4);
  } else {
    int xr = isu ? row : nu + row;
    uint4 u = *(const uint4*)(x + (size_t)xr * 32 + 4 * j);
    float* o = out + dst;
    float4 t0 = *(float4*)o;
    float4 t1 = *(float4*)(o + 4);
    t0.x += bf_lo(u.x); t0.y += bf_hi(u.x); t0.z += bf_lo(u.y); t0.w += bf_hi(u.y);
    t1.x += bf_lo(u.z); t1.y += bf_hi(u.z); t1.z += bf_lo(u.w); t1.w += bf_hi(u.w);
    *(float4*)o = t0;
    *(float4*)(o + 4) = t1;
  }
}

// ---------------- finalize: /4, target dropout masks ----------------
__global__ void k_finalize(float* __restrict__ out, int batch,
                           uint32_t ku0, uint32_t ku1, uint32_t ki0, uint32_t ki1) {
  int j = blockIdx.x * 256 + threadIdx.x;
  int H = batch * 64;
  if (j >= 2 * H) return;
  bool is_u = j < H;
  int f = is_u ? j : j - H;
  size_t online = is_u ? (size_t)f : (size_t)2 * H + f;
  uint32_t k0 = is_u ? ku0 : ki0;
  uint32_t k1 = is_u ? ku1 : ki1;
  float o = out[online] * 0.25f;                       // acc / (N_LAYERS+1), exact
  bool present = (bits32(k0, k1, (uint32_t)f) >> 31) == 0u;  // bernoulli(0.5)
  out[online] = o;
  out[online + H] = present ? o * 2.0f : 0.0f;         // t / (1-0.5), exact
}

extern "C" void kernel_launch(void* const* d_in, const int* in_sizes, int n_in,
                              void* d_out, int out_size, void* d_ws, size_t ws_size,
                              hipStream_t stream) {
  const float* uemb  = (const float*)d_in[0];
  const float* iemb  = (const float*)d_in[1];
  const float* avals = (const float*)d_in[2];
  const int*   rows  = (const int*)d_in[3];
  const int*   cols  = (const int*)d_in[4];
  const int*   users = (const int*)d_in[5];
  const int*   items = (const int*)d_in[6];
  const int DIM = 64;
  const int NU = in_sizes[0] / DIM;
  const int NI = in_sizes[1] / DIM;
  const int NNZ = in_sizes[2];
  const int B = in_sizes[5];
  const int NN = NU + NI;
  float* out = (float*)d_out;
  (void)n_in; (void)out_size; (void)ws_size;

  // derived subkeys: split(key(1234), 3) fold-like = threefry(key, (0, i))
  uint32_t ke0, ke1, ku0, ku1, ki0, ki1;
  tf2x32(0u, 1234u, 0u, 0u, ke0, ke1);
  tf2x32(0u, 1234u, 0u, 1u, ku0, ku1);
  tf2x32(0u, 1234u, 0u, 2u, ki0, ki1);

  // workspace carve
  char* p = (char*)d_ws;
  auto carve = [&](size_t bytes) {
    char* r = p;
    p += (bytes + 255) & ~(size_t)255;
    return (void*)r;
  };
  uint32_t* X0    = (uint32_t*)carve((size_t)NN * 32 * 4);  // bf16x2 rows
  uint32_t* X1    = (uint32_t*)carve((size_t)NN * 32 * 4);
  int2*  slot     = (int2*)carve((size_t)NNZ * 8);
  int*   cnt      = (int*)carve((size_t)NN * 4);
  int*   row_ptr  = (int*)carve((size_t)(NN + 1) * 4);
  int*   nextc    = (int*)carve((size_t)NN * 4);
  uint8_t* fB     = (uint8_t*)carve((size_t)NN * 3);  // fB | f1 | f2
  uint8_t* f1     = fB + NN;
  uint8_t* f2     = fB + 2 * (size_t)NN;
  int*   list1    = (int*)carve((size_t)NN * 4);
  int*   list2    = (int*)carve((size_t)NN * 4);
  const int NB    = (NN + 255) / 256;
  int*   bsum     = (int*)carve((size_t)NB * 4);
  int*   bpref    = (int*)carve((size_t)(NB + 1) * 4);
  int*   bsum1    = (int*)carve((size_t)NB * 4);
  int*   bpref1   = (int*)carve((size_t)(NB + 1) * 4);   // bpref1[NB] = |list1|
  int*   bsum2    = (int*)carve((size_t)NB * 4);
  int*   bpref2   = (int*)carve((size_t)(NB + 1) * 4);   // bpref2[NB] = |list2|

  hipMemsetAsync(cnt, 0, (size_t)NN * 4, stream);
  hipMemsetAsync(fB, 0, (size_t)NN * 3, stream);

  const int gE = (NNZ + 255) / 256;
  const int gN = (NN + 255) / 256;
  k_count<<<gE, 256, 0, stream>>>(rows, NNZ, cnt, ke0, ke1);
  k_blocksum<<<NB, 256, 0, stream>>>(cnt, NN, bsum);
  k_scanb<<<1, 1024, 0, stream>>>(bsum, NB, bpref);
  k_scan_write<<<NB, 256, 0, stream>>>(cnt, NN, bpref, row_ptr, nextc);
  k_scatter<<<gE, 256, 0, stream>>>(avals, rows, cols, NNZ, nextc, slot, ke0, ke1);

  // frontier: f2 = batch ∪ N(batch); f1 = batch ∪ N(f2); scan-compact to lists
  const int gB = (2 * B + 255) / 256;
  k_mark_batch<<<gB, 256, 0, stream>>>(users, items, B, NU, fB, f1, f2);
  k_mark_neighbors<<<gN, 256, 0, stream>>>(fB, row_ptr, slot, NN, f2);
  k_mark_neighbors<<<gN, 256, 0, stream>>>(f2, row_ptr, slot, NN, f1);
  k_flagsum2<<<NB, 256, 0, stream>>>(f1, f2, NN, bsum1, bsum2);
  k_scanb2<<<1, 1024, 0, stream>>>(bsum1, bsum2, NB, bpref1, bpref2);
  k_compact2<<<NB, 256, 0, stream>>>(f1, f2, NN, bpref1, bpref2, list1, list2);

  const int gG = (2 * B + 31) / 32;   // 32 rows/block (8 lanes per row)
  const int gS = (NN + 31) / 32;      // upper bound; spmm exits past nrows

  // layer-0 contribution (the raw embeddings) into online slots
  k_gather<1><<<gG, 256, 0, stream>>>(X0, uemb, iemb, users, items, out, B, NU);

  // layer 1: X0 = A * emb (rows in list1), accumulate batch rows
  k_spmm<1><<<gS, 256, 0, stream>>>(row_ptr, slot, X1, uemb, iemb, X0, list1, bpref1 + NB, NU);
  k_gather<0><<<gG, 256, 0, stream>>>(X0, uemb, iemb, users, items, out, B, NU);
  // layer 2: X1 = A * X0 (rows in list2), accumulate batch rows
  k_spmm<0><<<gS, 256, 0, stream>>>(row_ptr, slot, X0, uemb, iemb, X1, list2, bpref2 + NB, NU);
  k_gather<0><<<gG, 256, 0, stream>>>(X1, uemb, iemb, users, items, out, B, NU);
  // layer 3: only the 2B gathered rows are ever read -> fuse into gather
  k_spmm_gather<<<gG, 256, 0, stream>>>(row_ptr, slot, X1, users, items, out, B, NU);

  const int gF = (2 * B * DIM + 255) / 256;
  k_finalize<<<gF, 256, 0, stream>>>(out, B, ku0, ku1, ki0, ki1);
}

// Round 7
// 175.322 us; speedup vs baseline: 1.6506x; 1.0806x over previous
//
#include <hip/hip_runtime.h>
#include <stdint.h>

// ---------------- JAX threefry2x32 (partitionable mode) ----------------
__host__ __device__ inline void tf2x32(uint32_t k0, uint32_t k1,
                                       uint32_t x0, uint32_t x1,
                                       uint32_t& o0, uint32_t& o1) {
  const uint32_t ks2 = k0 ^ k1 ^ 0x1BD11BDAu;
  x0 += k0; x1 += k1;
#define TFR(r) { x0 += x1; x1 = (x1 << (r)) | (x1 >> (32 - (r))); x1 ^= x0; }
  TFR(13) TFR(15) TFR(26) TFR(6)
  x0 += k1;  x1 += ks2 + 1u;
  TFR(17) TFR(29) TFR(16) TFR(24)
  x0 += ks2; x1 += k0 + 2u;
  TFR(13) TFR(15) TFR(26) TFR(6)
  x0 += k0;  x1 += k1 + 3u;
  TFR(17) TFR(29) TFR(16) TFR(24)
  x0 += k1;  x1 += ks2 + 4u;
  TFR(13) TFR(15) TFR(26) TFR(6)
  x0 += ks2; x1 += k0 + 5u;
#undef TFR
  o0 = x0; o1 = x1;
}

__host__ __device__ inline uint32_t bits32(uint32_t k0, uint32_t k1, uint32_t idx) {
  uint32_t a, b;
  tf2x32(k0, k1, 0u, idx, a, b);
  return a ^ b;
}

// keep-edge iff uniform >= 0.5 iff bit31 of bits set (floor(0.5+u) == 1)
__device__ inline bool edge_kept(uint32_t k0, uint32_t k1, uint32_t e) {
  return (bits32(k0, k1, e) >> 31) != 0u;
}

__device__ inline float bf_lo(uint32_t u) { return __uint_as_float(u << 16); }
__device__ inline float bf_hi(uint32_t u) { return __uint_as_float(u & 0xffff0000u); }
__device__ inline uint32_t bf_pack(float a, float b) {
  uint32_t lo = (__float_as_uint(a) + 0x8000u) >> 16;
  uint32_t hi = (__float_as_uint(b) + 0x8000u) & 0xffff0000u;
  return hi | lo;
}

__device__ inline void fma8_f32(float a[8], float v, const float4& x0, const float4& x1) {
  a[0] = fmaf(v, x0.x, a[0]); a[1] = fmaf(v, x0.y, a[1]);
  a[2] = fmaf(v, x0.z, a[2]); a[3] = fmaf(v, x0.w, a[3]);
  a[4] = fmaf(v, x1.x, a[4]); a[5] = fmaf(v, x1.y, a[5]);
  a[6] = fmaf(v, x1.z, a[6]); a[7] = fmaf(v, x1.w, a[7]);
}
__device__ inline void fma8_bf(float a[8], float v, const uint4& u) {
  a[0] = fmaf(v, bf_lo(u.x), a[0]); a[1] = fmaf(v, bf_hi(u.x), a[1]);
  a[2] = fmaf(v, bf_lo(u.y), a[2]); a[3] = fmaf(v, bf_hi(u.y), a[3]);
  a[4] = fmaf(v, bf_lo(u.z), a[4]); a[5] = fmaf(v, bf_hi(u.z), a[5]);
  a[6] = fmaf(v, bf_lo(u.w), a[6]); a[7] = fmaf(v, bf_hi(u.w), a[7]);
}

// ---------------- keep bits: packed mask + first-half block sums +
//                  item-half per-row counts, all in one pass ----------------
__global__ __launch_bounds__(1024) void k_keep(
    const int* __restrict__ rows, int E, int E2, int nu,
    unsigned long long* __restrict__ keepw, int* __restrict__ bsumE,
    int* __restrict__ cnt, uint32_t ke0, uint32_t ke1) {
  __shared__ int s[16];
  int e = blockIdx.x * 1024 + threadIdx.x;
  int lane = threadIdx.x & 63;
  int wid = threadIdx.x >> 6;
  bool kept = (e < E) && edge_kept(ke0, ke1, (uint32_t)e);
  unsigned long long m = __ballot(kept);
  int ws = blockIdx.x * 1024 + wid * 64;   // wave's first edge index
  if (lane == 0 && ws < E) keepw[ws >> 6] = m;
  // first-half kept count for this wave
  int nf = 0;
  if (ws + 64 <= E2) nf = __popcll(m);
  else if (ws < E2) nf = __popcll(m & ((1ull << (E2 - ws)) - 1ull));
  if (lane == 0) s[wid] = nf;
  __syncthreads();
  if (threadIdx.x == 0) {
    int t = 0;
    for (int i = 0; i < 16; ++i) t += s[i];
    bsumE[blockIdx.x] = t;
  }
  // item-half per-row count
  if (kept && e >= E2) atomicAdd(&cnt[rows[e] - nu], 1);
}

// single block, 1024 threads, scans up to 2048 block sums -> exclusive prefix
// (bpref[0]=0, bpref[nb]=total)
__device__ inline void scan_block_1024(const int* __restrict__ bsum, int nb,
                                       int* __restrict__ bpref,
                                       int* a, int* b) {
  int t = threadIdx.x;
  for (int i = t; i < 2048; i += 1024) a[i] = (i < nb) ? bsum[i] : 0;
  __syncthreads();
  int* cur = a; int* nxt = b;
  for (int off = 1; off < 2048; off <<= 1) {
    for (int i = t; i < 2048; i += 1024)
      nxt[i] = cur[i] + (i >= off ? cur[i - off] : 0);
    __syncthreads();
    int* tmp = cur; cur = nxt; nxt = tmp;
  }
  for (int i = t; i <= nb; i += 1024)
    bpref[i] = (i == 0) ? 0 : cur[i - 1];
  __syncthreads();
}

// scan two block-sum arrays in one single-block kernel
__global__ void k_scanb2x(const int* __restrict__ bsumA, int nbA, int* __restrict__ bprefA,
                          const int* __restrict__ bsumB, int nbB, int* __restrict__ bprefB) {
  __shared__ int a[2048], b[2048];
  scan_block_1024(bsumA, nbA, bprefA, a, b);
  scan_block_1024(bsumB, nbB, bprefB, a, b);
}

__global__ void k_blocksum(const int* __restrict__ cnt, int n, int* __restrict__ bsum) {
  __shared__ int s[256];
  int i = blockIdx.x * 256 + threadIdx.x;
  s[threadIdx.x] = (i < n) ? cnt[i] : 0;
  __syncthreads();
  for (int off = 128; off > 0; off >>= 1) {
    if (threadIdx.x < off) s[threadIdx.x] += s[threadIdx.x + off];
    __syncthreads();
  }
  if (threadIdx.x == 0) bsum[blockIdx.x] = s[0];
}

__global__ void k_scan_write(const int* __restrict__ cnt, int n, const int* __restrict__ bpref,
                             int* __restrict__ row_ptr, int* __restrict__ nextc) {
  __shared__ int a[256], b[256];
  int t = threadIdx.x;
  int i = blockIdx.x * 256 + t;
  int v = (i < n) ? cnt[i] : 0;
  a[t] = v;
  __syncthreads();
  int* cur = a; int* nxt = b;
  for (int off = 1; off < 256; off <<= 1) {
    nxt[t] = cur[t] + (t >= off ? cur[t - off] : 0);
    __syncthreads();
    int* tmp = cur; cur = nxt; nxt = tmp;
  }
  int incl = cur[t] + bpref[blockIdx.x];
  int excl = incl - v;
  if (i < n) { row_ptr[i] = excl; nextc[i] = excl; }
  if (i == n - 1) row_ptr[n] = incl;
}

// ---- user-half compaction: coalesced writes (kept edges stay row-sorted),
//      row_ptr_u from boundaries of the sorted rows array. Deterministic. ----
__global__ __launch_bounds__(1024) void k_compactU(
    const int* __restrict__ rows, const int* __restrict__ cols,
    const float* __restrict__ avals, const unsigned long long* __restrict__ keepw,
    const int* __restrict__ bprefE, int E2, int nu, int nbE,
    int2* __restrict__ uslot, int* __restrict__ row_ptr_u) {
  __shared__ int a[1024], b[1024];
  int t = threadIdx.x;
  int e = blockIdx.x * 1024 + t;
  bool kept = (e < E2) && ((keepw[e >> 6] >> (e & 63)) & 1ull);
  a[t] = kept ? 1 : 0;
  __syncthreads();
  int* cur = a; int* nxt = b;
  for (int off = 1; off < 1024; off <<= 1) {
    nxt[t] = cur[t] + (t >= off ? cur[t - off] : 0);
    __syncthreads();
    int* tmp = cur; cur = nxt; nxt = tmp;
  }
  int excl = cur[t] - (kept ? 1 : 0);
  int pos = bprefE[blockIdx.x] + excl;
  if (kept) uslot[pos] = make_int2(cols[e], __float_as_int(avals[e] * 2.0f));
  if (e < E2) {
    int r = rows[e];
    int rp = (e == 0) ? -1 : rows[e - 1];
    for (int rr = rp + 1; rr <= r; ++rr) row_ptr_u[rr] = pos;
    if (e == E2 - 1) {
      int total = bprefE[nbE];
      for (int rr = r + 1; rr <= nu; ++rr) row_ptr_u[rr] = total;
    }
  }
}

// ---- item-half scatter (small: ~kept/2 random 8B writes into ~4MB) ----
__global__ void k_scatterI(const int* __restrict__ rows, const int* __restrict__ cols,
                           const float* __restrict__ avals,
                           const unsigned long long* __restrict__ keepw,
                           int E, int E2, int nu, int* __restrict__ nextc,
                           int2* __restrict__ islot) {
  int e = E2 + blockIdx.x * 256 + threadIdx.x;
  if (e >= E) return;
  if (!((keepw[e >> 6] >> (e & 63)) & 1ull)) return;
  int r = rows[e] - nu;
  int k = atomicAdd(&nextc[r], 1);
  islot[k] = make_int2(cols[e], __float_as_int(avals[e] * 2.0f));
}

// ---------------- frontier marking + scan-based compaction ----------------
__global__ void k_mark_batch(const int* __restrict__ users, const int* __restrict__ items,
                             int batch, int nu, uint8_t* fB, uint8_t* f1, uint8_t* f2) {
  int i = blockIdx.x * 256 + threadIdx.x;
  if (i >= 2 * batch) return;
  int r = (i < batch) ? users[i] : nu + items[i - batch];
  fB[r] = 1; f1[r] = 1; f2[r] = 1;
}

__global__ void k_mark_neighbors(const uint8_t* __restrict__ fin,
                                 const int* __restrict__ row_ptr_u,
                                 const int2* __restrict__ uslot,
                                 const int* __restrict__ row_ptr_i,
                                 const int2* __restrict__ islot,
                                 int n, int nu, uint8_t* __restrict__ fout) {
  int r = blockIdx.x * 256 + threadIdx.x;
  if (r >= n) return;
  if (!fin[r]) return;
  const int* rp = (r < nu) ? row_ptr_u : row_ptr_i;
  const int2* sl = (r < nu) ? uslot : islot;
  int rr = (r < nu) ? r : r - nu;
  int s = rp[rr], e = rp[rr + 1];
  for (int k = s; k < e; ++k) fout[sl[k].x] = 1;
}

__global__ void k_flagsum2(const uint8_t* __restrict__ f1, const uint8_t* __restrict__ f2,
                           int n, int* __restrict__ bsum1, int* __restrict__ bsum2) {
  __shared__ int s1[256], s2[256];
  int i = blockIdx.x * 256 + threadIdx.x;
  s1[threadIdx.x] = (i < n) ? (int)f1[i] : 0;
  s2[threadIdx.x] = (i < n) ? (int)f2[i] : 0;
  __syncthreads();
  for (int off = 128; off > 0; off >>= 1) {
    if (threadIdx.x < off) {
      s1[threadIdx.x] += s1[threadIdx.x + off];
      s2[threadIdx.x] += s2[threadIdx.x + off];
    }
    __syncthreads();
  }
  if (threadIdx.x == 0) { bsum1[blockIdx.x] = s1[0]; bsum2[blockIdx.x] = s2[0]; }
}

__global__ void k_compact2(const uint8_t* __restrict__ f1, const uint8_t* __restrict__ f2,
                           int n, const int* __restrict__ bpref1,
                           const int* __restrict__ bpref2,
                           int* __restrict__ list1, int* __restrict__ list2) {
  __shared__ int a[256], b[256];
  int t = threadIdx.x;
  int i = blockIdx.x * 256 + t;

  int v = (i < n) ? (int)f1[i] : 0;
  a[t] = v;
  __syncthreads();
  int* cur = a; int* nxt = b;
  for (int off = 1; off < 256; off <<= 1) {
    nxt[t] = cur[t] + (t >= off ? cur[t - off] : 0);
    __syncthreads();
    int* tmp = cur; cur = nxt; nxt = tmp;
  }
  if (v) list1[bpref1[blockIdx.x] + cur[t] - 1] = i;
  __syncthreads();

  v = (i < n) ? (int)f2[i] : 0;
  a[t] = v;
  __syncthreads();
  cur = a; nxt = b;
  for (int off = 1; off < 256; off <<= 1) {
    nxt[t] = cur[t] + (t >= off ? cur[t - off] : 0);
    __syncthreads();
    int* tmp = cur; cur = nxt; nxt = tmp;
  }
  if (v) list2[bpref2[blockIdx.x] + cur[t] - 1] = i;
}

// -------- SPMM: 8 lanes per row (lane owns 8 dims), 8 rows per wave --------
// X buffers are bf16x2-packed (uint32, 32 words per row).
template <int FIRST>
__global__ __launch_bounds__(256) void k_spmm(
    const int* __restrict__ row_ptr_u, const int2* __restrict__ uslot,
    const int* __restrict__ row_ptr_i, const int2* __restrict__ islot,
    const uint32_t* __restrict__ xin, const float* __restrict__ uemb,
    const float* __restrict__ iemb, uint32_t* __restrict__ xout,
    const int* __restrict__ rowlist, const int* __restrict__ nrows_p, int nu) {
  int nrows = *nrows_p;
  int i = blockIdx.x * 32 + (threadIdx.x >> 3);
  if (i >= nrows) return;
  int r = rowlist[i];
  int j = threadIdx.x & 7;
  bool isu = r < nu;
  const int* rp = isu ? row_ptr_u : row_ptr_i;
  const int2* sl = isu ? uslot : islot;
  int rr = isu ? r : r - nu;
  int s = rp[rr], e = rp[rr + 1];
  float a[8] = {0, 0, 0, 0, 0, 0, 0, 0};
  for (int k = s; k < e; k += 2) {
    int2 s0 = sl[k];
    bool has1 = (k + 1 < e);
    int2 s1 = sl[has1 ? k + 1 : k];
    float v0 = __int_as_float(s0.y);
    float v1 = has1 ? __int_as_float(s1.y) : 0.0f;
    if (FIRST) {
      const float* p0 = (s0.x < nu) ? uemb + (size_t)s0.x * 64
                                    : iemb + (size_t)(s0.x - nu) * 64;
      const float* p1 = (s1.x < nu) ? uemb + (size_t)s1.x * 64
                                    : iemb + (size_t)(s1.x - nu) * 64;
      float4 xa0 = *(const float4*)(p0 + 8 * j);
      float4 xb0 = *(const float4*)(p0 + 8 * j + 4);
      float4 xa1 = *(const float4*)(p1 + 8 * j);
      float4 xb1 = *(const float4*)(p1 + 8 * j + 4);
      fma8_f32(a, v0, xa0, xb0);
      fma8_f32(a, v1, xa1, xb1);
    } else {
      uint4 u0 = *(const uint4*)(xin + (size_t)s0.x * 32 + 4 * j);
      uint4 u1 = *(const uint4*)(xin + (size_t)s1.x * 32 + 4 * j);
      fma8_bf(a, v0, u0);
      fma8_bf(a, v1, u1);
    }
  }
  uint4 o;
  o.x = bf_pack(a[0], a[1]); o.y = bf_pack(a[2], a[3]);
  o.z = bf_pack(a[4], a[5]); o.w = bf_pack(a[6], a[7]);
  *(uint4*)(xout + (size_t)r * 32 + 4 * j) = o;
}

// ---- layer-3 SPMM fused into the batch gather: only 2B rows needed ----
__global__ __launch_bounds__(256) void k_spmm_gather(
    const int* __restrict__ row_ptr_u, const int2* __restrict__ uslot,
    const int* __restrict__ row_ptr_i, const int2* __restrict__ islot,
    const uint32_t* __restrict__ xin, const int* __restrict__ users,
    const int* __restrict__ items, float* __restrict__ out,
    int batch, int nu) {
  int b = blockIdx.x * 32 + (threadIdx.x >> 3);
  if (b >= 2 * batch) return;
  int j = threadIdx.x & 7;
  size_t H = (size_t)batch * 64;
  const int* rp; const int2* sl; int rr; size_t dst;
  if (b < batch) {
    rr = users[b];
    rp = row_ptr_u; sl = uslot;
    dst = (size_t)b * 64;
  } else {
    int bi = b - batch;
    rr = items[bi];
    rp = row_ptr_i; sl = islot;
    dst = 2 * H + (size_t)bi * 64;
  }
  int s = rp[rr], e = rp[rr + 1];
  float a[8] = {0, 0, 0, 0, 0, 0, 0, 0};
  for (int k = s; k < e; k += 2) {
    int2 s0 = sl[k];
    bool has1 = (k + 1 < e);
    int2 s1 = sl[has1 ? k + 1 : k];
    float v0 = __int_as_float(s0.y);
    float v1 = has1 ? __int_as_float(s1.y) : 0.0f;
    uint4 u0 = *(const uint4*)(xin + (size_t)s0.x * 32 + 4 * j);
    uint4 u1 = *(const uint4*)(xin + (size_t)s1.x * 32 + 4 * j);
    fma8_bf(a, v0, u0);
    fma8_bf(a, v1, u1);
  }
  float* o = out + dst + 8 * j;
  float4 t0 = *(float4*)o;
  float4 t1 = *(float4*)(o + 4);
  t0.x += a[0]; t0.y += a[1]; t0.z += a[2]; t0.w += a[3];
  t1.x += a[4]; t1.y += a[5]; t1.z += a[6]; t1.w += a[7];
  *(float4*)o = t0;
  *(float4*)(o + 4) = t1;
}

// ---------------- batch gather, accumulated into d_out ----------------
// out layout: [u_online | u_target | i_online | i_target], H = B*64 each.
template <int INIT>
__global__ void k_gather(const uint32_t* __restrict__ x, const float* __restrict__ uemb,
                         const float* __restrict__ iemb, const int* __restrict__ users,
                         const int* __restrict__ items, float* __restrict__ out,
                         int batch, int nu) {
  int b = blockIdx.x * 32 + (threadIdx.x >> 3);
  if (b >= 2 * batch) return;
  int j = threadIdx.x & 7;
  size_t H = (size_t)batch * 64;
  int row; size_t dst; bool isu = b < batch;
  if (isu) {
    row = users[b];
    dst = (size_t)b * 64 + 8 * j;
  } else {
    int bi = b - batch;
    row = items[bi];
    dst = 2 * H + (size_t)bi * 64 + 8 * j;
  }
  if (INIT) {
    const float* p = (isu ? uemb + (size_t)row * 64 : iemb + (size_t)row * 64) + 8 * j;
    *(float4*)(out + dst) = *(const float4*)p;
    *(float4*)(out + dst + 4) = *(const float4*)(p + 4);
  } else {
    int xr = isu ? row : nu + row;
    uint4 u = *(const uint4*)(x + (size_t)xr * 32 + 4 * j);
    float* o = out + dst;
    float4 t0 = *(float4*)o;
    float4 t1 = *(float4*)(o + 4);
    t0.x += bf_lo(u.x); t0.y += bf_hi(u.x); t0.z += bf_lo(u.y); t0.w += bf_hi(u.y);
    t1.x += bf_lo(u.z); t1.y += bf_hi(u.z); t1.z += bf_lo(u.w); t1.w += bf_hi(u.w);
    *(float4*)o = t0;
    *(float4*)(o + 4) = t1;
  }
}

// ---------------- finalize: /4, target dropout masks ----------------
__global__ void k_finalize(float* __restrict__ out, int batch,
                           uint32_t ku0, uint32_t ku1, uint32_t ki0, uint32_t ki1) {
  int j = blockIdx.x * 256 + threadIdx.x;
  int H = batch * 64;
  if (j >= 2 * H) return;
  bool is_u = j < H;
  int f = is_u ? j : j - H;
  size_t online = is_u ? (size_t)f : (size_t)2 * H + f;
  uint32_t k0 = is_u ? ku0 : ki0;
  uint32_t k1 = is_u ? ku1 : ki1;
  float o = out[online] * 0.25f;                       // acc / (N_LAYERS+1), exact
  bool present = (bits32(k0, k1, (uint32_t)f) >> 31) == 0u;  // bernoulli(0.5)
  out[online] = o;
  out[online + H] = present ? o * 2.0f : 0.0f;         // t / (1-0.5), exact
}

extern "C" void kernel_launch(void* const* d_in, const int* in_sizes, int n_in,
                              void* d_out, int out_size, void* d_ws, size_t ws_size,
                              hipStream_t stream) {
  const float* uemb  = (const float*)d_in[0];
  const float* iemb  = (const float*)d_in[1];
  const float* avals = (const float*)d_in[2];
  const int*   rows  = (const int*)d_in[3];
  const int*   cols  = (const int*)d_in[4];
  const int*   users = (const int*)d_in[5];
  const int*   items = (const int*)d_in[6];
  const int DIM = 64;
  const int NU = in_sizes[0] / DIM;
  const int NI = in_sizes[1] / DIM;
  const int E  = in_sizes[2];
  const int E2 = E / 2;             // first half: user rows, sorted by row
  const int B = in_sizes[5];
  const int NN = NU + NI;
  float* out = (float*)d_out;
  (void)n_in; (void)out_size; (void)ws_size;

  // derived subkeys: split(key(1234), 3) fold-like = threefry(key, (0, i))
  uint32_t ke0, ke1, ku0, ku1, ki0, ki1;
  tf2x32(0u, 1234u, 0u, 0u, ke0, ke1);
  tf2x32(0u, 1234u, 0u, 1u, ku0, ku1);
  tf2x32(0u, 1234u, 0u, 2u, ki0, ki1);

  // workspace carve
  char* p = (char*)d_ws;
  auto carve = [&](size_t bytes) {
    char* r = p;
    p += (bytes + 255) & ~(size_t)255;
    return (void*)r;
  };
  uint32_t* X0    = (uint32_t*)carve((size_t)NN * 32 * 4);  // bf16x2 rows
  uint32_t* X1    = (uint32_t*)carve((size_t)NN * 32 * 4);
  int2*  uslot    = (int2*)carve((size_t)E2 * 8);
  int2*  islot    = (int2*)carve((size_t)(E - E2) * 8);
  unsigned long long* keepw = (unsigned long long*)carve(((size_t)E / 64 + 2) * 8);
  int*   cnt      = (int*)carve((size_t)NI * 4);
  int*   row_ptr_u = (int*)carve((size_t)(NU + 1) * 4);
  int*   row_ptr_i = (int*)carve((size_t)(NI + 1) * 4);
  int*   nextc    = (int*)carve((size_t)NI * 4);
  uint8_t* fB     = (uint8_t*)carve((size_t)NN * 3);  // fB | f1 | f2
  uint8_t* f1     = fB + NN;
  uint8_t* f2     = fB + 2 * (size_t)NN;
  int*   list1    = (int*)carve((size_t)NN * 4);
  int*   list2    = (int*)carve((size_t)NN * 4);
  const int GK    = (E + 1023) / 1024;      // k_keep grid
  const int NBE   = (E2 + 1023) / 1024;     // first-half scan blocks
  const int NBI   = (NI + 255) / 256;       // item-count scan blocks
  const int NB    = (NN + 255) / 256;       // frontier scan blocks
  int*   bsumE    = (int*)carve((size_t)GK * 4);
  int*   bprefE   = (int*)carve((size_t)(NBE + 1) * 4);
  int*   bsumI    = (int*)carve((size_t)NBI * 4);
  int*   bprefI   = (int*)carve((size_t)(NBI + 1) * 4);
  int*   bsum1    = (int*)carve((size_t)NB * 4);
  int*   bpref1   = (int*)carve((size_t)(NB + 1) * 4);   // bpref1[NB] = |list1|
  int*   bsum2    = (int*)carve((size_t)NB * 4);
  int*   bpref2   = (int*)carve((size_t)(NB + 1) * 4);   // bpref2[NB] = |list2|

  hipMemsetAsync(cnt, 0, (size_t)NI * 4, stream);
  hipMemsetAsync(fB, 0, (size_t)NN * 3, stream);

  // CSR build: deterministic coalesced compaction (user half, row-sorted) +
  // small atomic scatter (item half)
  k_keep<<<GK, 1024, 0, stream>>>(rows, E, E2, NU, keepw, bsumE, cnt, ke0, ke1);
  k_blocksum<<<NBI, 256, 0, stream>>>(cnt, NI, bsumI);
  k_scanb2x<<<1, 1024, 0, stream>>>(bsumE, NBE, bprefE, bsumI, NBI, bprefI);
  k_scan_write<<<NBI, 256, 0, stream>>>(cnt, NI, bprefI, row_ptr_i, nextc);
  k_compactU<<<NBE, 1024, 0, stream>>>(rows, cols, avals, keepw, bprefE, E2, NU, NBE,
                                       uslot, row_ptr_u);
  {
    const int gI = (E - E2 + 255) / 256;
    k_scatterI<<<gI, 256, 0, stream>>>(rows, cols, avals, keepw, E, E2, NU, nextc, islot);
  }

  // frontier: f2 = batch ∪ N(batch); f1 = batch ∪ N(f2); scan-compact to lists
  const int gB = (2 * B + 255) / 256;
  const int gN = (NN + 255) / 256;
  k_mark_batch<<<gB, 256, 0, stream>>>(users, items, B, NU, fB, f1, f2);
  k_mark_neighbors<<<gN, 256, 0, stream>>>(fB, row_ptr_u, uslot, row_ptr_i, islot, NN, NU, f2);
  k_mark_neighbors<<<gN, 256, 0, stream>>>(f2, row_ptr_u, uslot, row_ptr_i, islot, NN, NU, f1);
  k_flagsum2<<<NB, 256, 0, stream>>>(f1, f2, NN, bsum1, bsum2);
  k_scanb2x<<<1, 1024, 0, stream>>>(bsum1, NB, bpref1, bsum2, NB, bpref2);
  k_compact2<<<NB, 256, 0, stream>>>(f1, f2, NN, bpref1, bpref2, list1, list2);

  const int gG = (2 * B + 31) / 32;   // 32 rows/block (8 lanes per row)
  const int gS = (NN + 31) / 32;      // upper bound; spmm exits past nrows

  // layer-0 contribution (the raw embeddings) into online slots
  k_gather<1><<<gG, 256, 0, stream>>>(X0, uemb, iemb, users, items, out, B, NU);

  // layer 1: X0 = A * emb (rows in list1), accumulate batch rows
  k_spmm<1><<<gS, 256, 0, stream>>>(row_ptr_u, uslot, row_ptr_i, islot, X1,
                                    uemb, iemb, X0, list1, bpref1 + NB, NU);
  k_gather<0><<<gG, 256, 0, stream>>>(X0, uemb, iemb, users, items, out, B, NU);
  // layer 2: X1 = A * X0 (rows in list2), accumulate batch rows
  k_spmm<0><<<gS, 256, 0, stream>>>(row_ptr_u, uslot, row_ptr_i, islot, X0,
                                    uemb, iemb, X1, list2, bpref2 + NB, NU);
  k_gather<0><<<gG, 256, 0, stream>>>(X1, uemb, iemb, users, items, out, B, NU);
  // layer 3: only the 2B gathered rows are ever read -> fuse into gather
  k_spmm_gather<<<gG, 256, 0, stream>>>(row_ptr_u, uslot, row_ptr_i, islot, X1,
                                        users, items, out, B, NU);

  const int gF = (2 * B * DIM + 255) / 256;
  k_finalize<<<gF, 256, 0, stream>>>(out, B, ku0, ku1, ki0, ki1);
}

// Round 8
// 161.102 us; speedup vs baseline: 1.7963x; 1.0883x over previous
//
#include <hip/hip_runtime.h>
#include <stdint.h>

// ---------------- JAX threefry2x32 (partitionable mode) ----------------
__host__ __device__ inline void tf2x32(uint32_t k0, uint32_t k1,
                                       uint32_t x0, uint32_t x1,
                                       uint32_t& o0, uint32_t& o1) {
  const uint32_t ks2 = k0 ^ k1 ^ 0x1BD11BDAu;
  x0 += k0; x1 += k1;
#define TFR(r) { x0 += x1; x1 = (x1 << (r)) | (x1 >> (32 - (r))); x1 ^= x0; }
  TFR(13) TFR(15) TFR(26) TFR(6)
  x0 += k1;  x1 += ks2 + 1u;
  TFR(17) TFR(29) TFR(16) TFR(24)
  x0 += ks2; x1 += k0 + 2u;
  TFR(13) TFR(15) TFR(26) TFR(6)
  x0 += k0;  x1 += k1 + 3u;
  TFR(17) TFR(29) TFR(16) TFR(24)
  x0 += k1;  x1 += ks2 + 4u;
  TFR(13) TFR(15) TFR(26) TFR(6)
  x0 += ks2; x1 += k0 + 5u;
#undef TFR
  o0 = x0; o1 = x1;
}

__host__ __device__ inline uint32_t bits32(uint32_t k0, uint32_t k1, uint32_t idx) {
  uint32_t a, b;
  tf2x32(k0, k1, 0u, idx, a, b);
  return a ^ b;
}

// keep-edge iff uniform >= 0.5 iff bit31 of bits set (floor(0.5+u) == 1)
__device__ inline bool edge_kept(uint32_t k0, uint32_t k1, uint32_t e) {
  return (bits32(k0, k1, e) >> 31) != 0u;
}

__device__ inline float bf_lo(uint32_t u) { return __uint_as_float(u << 16); }
__device__ inline float bf_hi(uint32_t u) { return __uint_as_float(u & 0xffff0000u); }
__device__ inline uint32_t bf_pack(float a, float b) {
  uint32_t lo = (__float_as_uint(a) + 0x8000u) >> 16;
  uint32_t hi = (__float_as_uint(b) + 0x8000u) & 0xffff0000u;
  return hi | lo;
}

__device__ inline void fma8_f32(float a[8], float v, const float4& x0, const float4& x1) {
  a[0] = fmaf(v, x0.x, a[0]); a[1] = fmaf(v, x0.y, a[1]);
  a[2] = fmaf(v, x0.z, a[2]); a[3] = fmaf(v, x0.w, a[3]);
  a[4] = fmaf(v, x1.x, a[4]); a[5] = fmaf(v, x1.y, a[5]);
  a[6] = fmaf(v, x1.z, a[6]); a[7] = fmaf(v, x1.w, a[7]);
}
__device__ inline void fma8_bf(float a[8], float v, const uint4& u) {
  a[0] = fmaf(v, bf_lo(u.x), a[0]); a[1] = fmaf(v, bf_hi(u.x), a[1]);
  a[2] = fmaf(v, bf_lo(u.y), a[2]); a[3] = fmaf(v, bf_hi(u.y), a[3]);
  a[4] = fmaf(v, bf_lo(u.z), a[4]); a[5] = fmaf(v, bf_hi(u.z), a[5]);
  a[6] = fmaf(v, bf_lo(u.w), a[6]); a[7] = fmaf(v, bf_hi(u.w), a[7]);
}

// ---------------- keep bits: packed mask + first-half block sums +
//                  item-half per-row counts, all in one pass ----------------
__global__ __launch_bounds__(1024) void k_keep(
    const int* __restrict__ rows, int E, int E2, int nu,
    unsigned long long* __restrict__ keepw, int* __restrict__ bsumE,
    int* __restrict__ cnt, uint32_t ke0, uint32_t ke1) {
  __shared__ int s[16];
  int e = blockIdx.x * 1024 + threadIdx.x;
  int lane = threadIdx.x & 63;
  int wid = threadIdx.x >> 6;
  bool kept = (e < E) && edge_kept(ke0, ke1, (uint32_t)e);
  unsigned long long m = __ballot(kept);
  int ws = blockIdx.x * 1024 + wid * 64;   // wave's first edge index
  if (lane == 0 && ws < E) keepw[ws >> 6] = m;
  // first-half kept count for this wave
  int nf = 0;
  if (ws + 64 <= E2) nf = __popcll(m);
  else if (ws < E2) nf = __popcll(m & ((1ull << (E2 - ws)) - 1ull));
  if (lane == 0) s[wid] = nf;
  __syncthreads();
  if (threadIdx.x == 0) {
    int t = 0;
    for (int i = 0; i < 16; ++i) t += s[i];
    bsumE[blockIdx.x] = t;
  }
  // item-half per-row count
  if (kept && e >= E2) atomicAdd(&cnt[rows[e] - nu], 1);
}

// single block, 1024 threads, scans up to 2048 block sums -> exclusive prefix
// (bpref[0]=0, bpref[nb]=total)
__device__ inline void scan_block_1024(const int* __restrict__ bsum, int nb,
                                       int* __restrict__ bpref,
                                       int* a, int* b) {
  int t = threadIdx.x;
  for (int i = t; i < 2048; i += 1024) a[i] = (i < nb) ? bsum[i] : 0;
  __syncthreads();
  int* cur = a; int* nxt = b;
  for (int off = 1; off < 2048; off <<= 1) {
    for (int i = t; i < 2048; i += 1024)
      nxt[i] = cur[i] + (i >= off ? cur[i - off] : 0);
    __syncthreads();
    int* tmp = cur; cur = nxt; nxt = tmp;
  }
  for (int i = t; i <= nb; i += 1024)
    bpref[i] = (i == 0) ? 0 : cur[i - 1];
  __syncthreads();
}

// scan two block-sum arrays in one single-block kernel
__global__ void k_scanb2x(const int* __restrict__ bsumA, int nbA, int* __restrict__ bprefA,
                          const int* __restrict__ bsumB, int nbB, int* __restrict__ bprefB) {
  __shared__ int a[2048], b[2048];
  scan_block_1024(bsumA, nbA, bprefA, a, b);
  scan_block_1024(bsumB, nbB, bprefB, a, b);
}

__global__ void k_blocksum(const int* __restrict__ cnt, int n, int* __restrict__ bsum) {
  __shared__ int s[256];
  int i = blockIdx.x * 256 + threadIdx.x;
  s[threadIdx.x] = (i < n) ? cnt[i] : 0;
  __syncthreads();
  for (int off = 128; off > 0; off >>= 1) {
    if (threadIdx.x < off) s[threadIdx.x] += s[threadIdx.x + off];
    __syncthreads();
  }
  if (threadIdx.x == 0) bsum[blockIdx.x] = s[0];
}

__global__ void k_scan_write(const int* __restrict__ cnt, int n, const int* __restrict__ bpref,
                             int* __restrict__ row_ptr, int* __restrict__ nextc) {
  __shared__ int a[256], b[256];
  int t = threadIdx.x;
  int i = blockIdx.x * 256 + t;
  int v = (i < n) ? cnt[i] : 0;
  a[t] = v;
  __syncthreads();
  int* cur = a; int* nxt = b;
  for (int off = 1; off < 256; off <<= 1) {
    nxt[t] = cur[t] + (t >= off ? cur[t - off] : 0);
    __syncthreads();
    int* tmp = cur; cur = nxt; nxt = tmp;
  }
  int incl = cur[t] + bpref[blockIdx.x];
  int excl = incl - v;
  if (i < n) { row_ptr[i] = excl; nextc[i] = excl; }
  if (i == n - 1) row_ptr[n] = incl;
}

// ---- user-half compaction: coalesced writes (kept edges stay row-sorted),
//      row_ptr_u from boundaries of the sorted rows array. Deterministic. ----
__global__ __launch_bounds__(1024) void k_compactU(
    const int* __restrict__ rows, const int* __restrict__ cols,
    const float* __restrict__ avals, const unsigned long long* __restrict__ keepw,
    const int* __restrict__ bprefE, int E2, int nu, int nbE,
    int2* __restrict__ uslot, int* __restrict__ row_ptr_u) {
  __shared__ int a[1024], b[1024];
  int t = threadIdx.x;
  int e = blockIdx.x * 1024 + t;
  bool kept = (e < E2) && ((keepw[e >> 6] >> (e & 63)) & 1ull);
  a[t] = kept ? 1 : 0;
  __syncthreads();
  int* cur = a; int* nxt = b;
  for (int off = 1; off < 1024; off <<= 1) {
    nxt[t] = cur[t] + (t >= off ? cur[t - off] : 0);
    __syncthreads();
    int* tmp = cur; cur = nxt; nxt = tmp;
  }
  int excl = cur[t] - (kept ? 1 : 0);
  int pos = bprefE[blockIdx.x] + excl;
  if (kept) uslot[pos] = make_int2(cols[e], __float_as_int(avals[e] * 2.0f));
  if (e < E2) {
    int r = rows[e];
    int rp = (e == 0) ? -1 : rows[e - 1];
    for (int rr = rp + 1; rr <= r; ++rr) row_ptr_u[rr] = pos;
    if (e == E2 - 1) {
      int total = bprefE[nbE];
      for (int rr = r + 1; rr <= nu; ++rr) row_ptr_u[rr] = total;
    }
  }
}

// ---- item-half scatter (small: ~kept/2 random 8B writes into ~4MB) ----
__global__ void k_scatterI(const int* __restrict__ rows, const int* __restrict__ cols,
                           const float* __restrict__ avals,
                           const unsigned long long* __restrict__ keepw,
                           int E, int E2, int nu, int* __restrict__ nextc,
                           int2* __restrict__ islot) {
  int e = E2 + blockIdx.x * 256 + threadIdx.x;
  if (e >= E) return;
  if (!((keepw[e >> 6] >> (e & 63)) & 1ull)) return;
  int r = rows[e] - nu;
  int k = atomicAdd(&nextc[r], 1);
  islot[k] = make_int2(cols[e], __float_as_int(avals[e] * 2.0f));
}

// ---------------- frontier marking + scan-based compaction ----------------
__global__ void k_mark_batch(const int* __restrict__ users, const int* __restrict__ items,
                             int batch, int nu, uint8_t* fB, uint8_t* f1, uint8_t* f2) {
  int i = blockIdx.x * 256 + threadIdx.x;
  if (i >= 2 * batch) return;
  int r = (i < batch) ? users[i] : nu + items[i - batch];
  fB[r] = 1; f1[r] = 1; f2[r] = 1;
}

__global__ void k_mark_neighbors(const uint8_t* __restrict__ fin,
                                 const int* __restrict__ row_ptr_u,
                                 const int2* __restrict__ uslot,
                                 const int* __restrict__ row_ptr_i,
                                 const int2* __restrict__ islot,
                                 int n, int nu, uint8_t* __restrict__ fout) {
  int r = blockIdx.x * 256 + threadIdx.x;
  if (r >= n) return;
  if (!fin[r]) return;
  const int* rp = (r < nu) ? row_ptr_u : row_ptr_i;
  const int2* sl = (r < nu) ? uslot : islot;
  int rr = (r < nu) ? r : r - nu;
  int s = rp[rr], e = rp[rr + 1];
  for (int k = s; k < e; ++k) fout[sl[k].x] = 1;
}

__global__ void k_flagsum2(const uint8_t* __restrict__ f1, const uint8_t* __restrict__ f2,
                           int n, int* __restrict__ bsum1, int* __restrict__ bsum2) {
  __shared__ int s1[256], s2[256];
  int i = blockIdx.x * 256 + threadIdx.x;
  s1[threadIdx.x] = (i < n) ? (int)f1[i] : 0;
  s2[threadIdx.x] = (i < n) ? (int)f2[i] : 0;
  __syncthreads();
  for (int off = 128; off > 0; off >>= 1) {
    if (threadIdx.x < off) {
      s1[threadIdx.x] += s1[threadIdx.x + off];
      s2[threadIdx.x] += s2[threadIdx.x + off];
    }
    __syncthreads();
  }
  if (threadIdx.x == 0) { bsum1[blockIdx.x] = s1[0]; bsum2[blockIdx.x] = s2[0]; }
}

__global__ void k_compact2(const uint8_t* __restrict__ f1, const uint8_t* __restrict__ f2,
                           int n, const int* __restrict__ bpref1,
                           const int* __restrict__ bpref2,
                           int* __restrict__ list1, int* __restrict__ list2) {
  __shared__ int a[256], b[256];
  int t = threadIdx.x;
  int i = blockIdx.x * 256 + t;

  int v = (i < n) ? (int)f1[i] : 0;
  a[t] = v;
  __syncthreads();
  int* cur = a; int* nxt = b;
  for (int off = 1; off < 256; off <<= 1) {
    nxt[t] = cur[t] + (t >= off ? cur[t - off] : 0);
    __syncthreads();
    int* tmp = cur; cur = nxt; nxt = tmp;
  }
  if (v) list1[bpref1[blockIdx.x] + cur[t] - 1] = i;
  __syncthreads();

  v = (i < n) ? (int)f2[i] : 0;
  a[t] = v;
  __syncthreads();
  cur = a; nxt = b;
  for (int off = 1; off < 256; off <<= 1) {
    nxt[t] = cur[t] + (t >= off ? cur[t - off] : 0);
    __syncthreads();
    int* tmp = cur; cur = nxt; nxt = tmp;
  }
  if (v) list2[bpref2[blockIdx.x] + cur[t] - 1] = i;
}

// -------- SPMM: 8 lanes per row (lane owns 8 dims), 4-edge unroll ----------
// X buffers are bf16x2-packed (uint32, 32 words per row).
template <int FIRST>
__global__ __launch_bounds__(256) void k_spmm(
    const int* __restrict__ row_ptr_u, const int2* __restrict__ uslot,
    const int* __restrict__ row_ptr_i, const int2* __restrict__ islot,
    const uint32_t* __restrict__ xin, const float* __restrict__ uemb,
    const float* __restrict__ iemb, uint32_t* __restrict__ xout,
    const int* __restrict__ rowlist, const int* __restrict__ nrows_p, int nu) {
  int nrows = *nrows_p;
  int i = blockIdx.x * 32 + (threadIdx.x >> 3);
  if (i >= nrows) return;
  int r = rowlist[i];
  int j = threadIdx.x & 7;
  bool isu = r < nu;
  const int* rp = isu ? row_ptr_u : row_ptr_i;
  const int2* sl = isu ? uslot : islot;
  int rr = isu ? r : r - nu;
  int s = rp[rr], e = rp[rr + 1];
  float a[8] = {0, 0, 0, 0, 0, 0, 0, 0};
  int last = e - 1;
  for (int k = s; k < e; k += 4) {
    int i1 = (k + 1 <= last) ? k + 1 : last;
    int i2 = (k + 2 <= last) ? k + 2 : last;
    int i3 = (k + 3 <= last) ? k + 3 : last;
    int2 s0 = sl[k], s1 = sl[i1], s2 = sl[i2], s3 = sl[i3];
    float v0 = __int_as_float(s0.y);
    float v1 = (k + 1 <= last) ? __int_as_float(s1.y) : 0.0f;
    float v2 = (k + 2 <= last) ? __int_as_float(s2.y) : 0.0f;
    float v3 = (k + 3 <= last) ? __int_as_float(s3.y) : 0.0f;
    if (FIRST) {
      const float* p0 = (s0.x < nu) ? uemb + (size_t)s0.x * 64
                                    : iemb + (size_t)(s0.x - nu) * 64;
      const float* p1 = (s1.x < nu) ? uemb + (size_t)s1.x * 64
                                    : iemb + (size_t)(s1.x - nu) * 64;
      const float* p2 = (s2.x < nu) ? uemb + (size_t)s2.x * 64
                                    : iemb + (size_t)(s2.x - nu) * 64;
      const float* p3 = (s3.x < nu) ? uemb + (size_t)s3.x * 64
                                    : iemb + (size_t)(s3.x - nu) * 64;
      float4 xa0 = *(const float4*)(p0 + 8 * j);
      float4 xb0 = *(const float4*)(p0 + 8 * j + 4);
      float4 xa1 = *(const float4*)(p1 + 8 * j);
      float4 xb1 = *(const float4*)(p1 + 8 * j + 4);
      float4 xa2 = *(const float4*)(p2 + 8 * j);
      float4 xb2 = *(const float4*)(p2 + 8 * j + 4);
      float4 xa3 = *(const float4*)(p3 + 8 * j);
      float4 xb3 = *(const float4*)(p3 + 8 * j + 4);
      fma8_f32(a, v0, xa0, xb0);
      fma8_f32(a, v1, xa1, xb1);
      fma8_f32(a, v2, xa2, xb2);
      fma8_f32(a, v3, xa3, xb3);
    } else {
      uint4 u0 = *(const uint4*)(xin + (size_t)s0.x * 32 + 4 * j);
      uint4 u1 = *(const uint4*)(xin + (size_t)s1.x * 32 + 4 * j);
      uint4 u2 = *(const uint4*)(xin + (size_t)s2.x * 32 + 4 * j);
      uint4 u3 = *(const uint4*)(xin + (size_t)s3.x * 32 + 4 * j);
      fma8_bf(a, v0, u0);
      fma8_bf(a, v1, u1);
      fma8_bf(a, v2, u2);
      fma8_bf(a, v3, u3);
    }
  }
  uint4 o;
  o.x = bf_pack(a[0], a[1]); o.y = bf_pack(a[2], a[3]);
  o.z = bf_pack(a[4], a[5]); o.w = bf_pack(a[6], a[7]);
  *(uint4*)(xout + (size_t)r * 32 + 4 * j) = o;
}

// ---- epilogue A (after layer 1): out_online = emb[row] + bf(X0[row]) ----
// out layout: [u_online | u_target | i_online | i_target], H = B*64 each.
__global__ void k_gatherA(const uint32_t* __restrict__ x0, const float* __restrict__ uemb,
                          const float* __restrict__ iemb, const int* __restrict__ users,
                          const int* __restrict__ items, float* __restrict__ out,
                          int batch, int nu) {
  int b = blockIdx.x * 32 + (threadIdx.x >> 3);
  if (b >= 2 * batch) return;
  int j = threadIdx.x & 7;
  size_t H = (size_t)batch * 64;
  int row; size_t dst; bool isu = b < batch;
  if (isu) {
    row = users[b];
    dst = (size_t)b * 64 + 8 * j;
  } else {
    int bi = b - batch;
    row = items[bi];
    dst = 2 * H + (size_t)bi * 64 + 8 * j;
  }
  const float* p = (isu ? uemb + (size_t)row * 64 : iemb + (size_t)row * 64) + 8 * j;
  float4 t0 = *(const float4*)p;
  float4 t1 = *(const float4*)(p + 4);
  int xr = isu ? row : nu + row;
  uint4 u = *(const uint4*)(x0 + (size_t)xr * 32 + 4 * j);
  t0.x += bf_lo(u.x); t0.y += bf_hi(u.x); t0.z += bf_lo(u.y); t0.w += bf_hi(u.y);
  t1.x += bf_lo(u.z); t1.y += bf_hi(u.z); t1.z += bf_lo(u.w); t1.w += bf_hi(u.w);
  *(float4*)(out + dst) = t0;
  *(float4*)(out + dst + 4) = t1;
}

// ---- epilogue tail: += bf(X1[row]) [layer 2] + SPMM(X1)[row] [layer 3],
//      then /4 and target dropout masks. One RMW pass over out. ----
__global__ __launch_bounds__(256) void k_tail(
    const int* __restrict__ row_ptr_u, const int2* __restrict__ uslot,
    const int* __restrict__ row_ptr_i, const int2* __restrict__ islot,
    const uint32_t* __restrict__ x1, const int* __restrict__ users,
    const int* __restrict__ items, float* __restrict__ out,
    int batch, int nu,
    uint32_t ku0, uint32_t ku1, uint32_t ki0, uint32_t ki1) {
  int b = blockIdx.x * 32 + (threadIdx.x >> 3);
  if (b >= 2 * batch) return;
  int j = threadIdx.x & 7;
  size_t H = (size_t)batch * 64;
  const int* rp; const int2* sl; int rr; size_t dst; int f0; uint32_t mk0, mk1;
  bool isu = b < batch;
  if (isu) {
    rr = users[b];
    rp = row_ptr_u; sl = uslot;
    dst = (size_t)b * 64 + 8 * j;
    f0 = b * 64 + 8 * j;
    mk0 = ku0; mk1 = ku1;
  } else {
    int bi = b - batch;
    rr = items[bi];
    rp = row_ptr_i; sl = islot;
    dst = 2 * H + (size_t)bi * 64 + 8 * j;
    f0 = bi * 64 + 8 * j;
    mk0 = ki0; mk1 = ki1;
  }
  // layer-3 SPMM accumulation from X1 (4-edge unroll)
  int s = rp[rr], e = rp[rr + 1];
  float a[8] = {0, 0, 0, 0, 0, 0, 0, 0};
  int last = e - 1;
  for (int k = s; k < e; k += 4) {
    int i1 = (k + 1 <= last) ? k + 1 : last;
    int i2 = (k + 2 <= last) ? k + 2 : last;
    int i3 = (k + 3 <= last) ? k + 3 : last;
    int2 s0 = sl[k], s1 = sl[i1], s2 = sl[i2], s3 = sl[i3];
    float v0 = __int_as_float(s0.y);
    float v1 = (k + 1 <= last) ? __int_as_float(s1.y) : 0.0f;
    float v2 = (k + 2 <= last) ? __int_as_float(s2.y) : 0.0f;
    float v3 = (k + 3 <= last) ? __int_as_float(s3.y) : 0.0f;
    uint4 u0 = *(const uint4*)(x1 + (size_t)s0.x * 32 + 4 * j);
    uint4 u1 = *(const uint4*)(x1 + (size_t)s1.x * 32 + 4 * j);
    uint4 u2 = *(const uint4*)(x1 + (size_t)s2.x * 32 + 4 * j);
    uint4 u3 = *(const uint4*)(x1 + (size_t)s3.x * 32 + 4 * j);
    fma8_bf(a, v0, u0);
    fma8_bf(a, v1, u1);
    fma8_bf(a, v2, u2);
    fma8_bf(a, v3, u3);
  }
  // layer-2 term: X1 at this row
  int xr = isu ? rr : nu + rr;
  uint4 u = *(const uint4*)(x1 + (size_t)xr * 32 + 4 * j);
  float* o = out + dst;
  float4 t0 = *(float4*)o;
  float4 t1 = *(float4*)(o + 4);
  // same per-element addition order as the unfused path: (+x1) then (+L3)
  t0.x += bf_lo(u.x); t0.y += bf_hi(u.x); t0.z += bf_lo(u.y); t0.w += bf_hi(u.y);
  t1.x += bf_lo(u.z); t1.y += bf_hi(u.z); t1.z += bf_lo(u.w); t1.w += bf_hi(u.w);
  t0.x += a[0]; t0.y += a[1]; t0.z += a[2]; t0.w += a[3];
  t1.x += a[4]; t1.y += a[5]; t1.z += a[6]; t1.w += a[7];
  // /4 (exact), target dropout (bernoulli(0.5): bit31==0 -> present, *2 exact)
  float ov[8] = {t0.x * 0.25f, t0.y * 0.25f, t0.z * 0.25f, t0.w * 0.25f,
                 t1.x * 0.25f, t1.y * 0.25f, t1.z * 0.25f, t1.w * 0.25f};
  float tv[8];
#pragma unroll
  for (int c = 0; c < 8; ++c) {
    bool present = (bits32(mk0, mk1, (uint32_t)(f0 + c)) >> 31) == 0u;
    tv[c] = present ? ov[c] * 2.0f : 0.0f;
  }
  *(float4*)o = make_float4(ov[0], ov[1], ov[2], ov[3]);
  *(float4*)(o + 4) = make_float4(ov[4], ov[5], ov[6], ov[7]);
  *(float4*)(o + H) = make_float4(tv[0], tv[1], tv[2], tv[3]);
  *(float4*)(o + H + 4) = make_float4(tv[4], tv[5], tv[6], tv[7]);
}

extern "C" void kernel_launch(void* const* d_in, const int* in_sizes, int n_in,
                              void* d_out, int out_size, void* d_ws, size_t ws_size,
                              hipStream_t stream) {
  const float* uemb  = (const float*)d_in[0];
  const float* iemb  = (const float*)d_in[1];
  const float* avals = (const float*)d_in[2];
  const int*   rows  = (const int*)d_in[3];
  const int*   cols  = (const int*)d_in[4];
  const int*   users = (const int*)d_in[5];
  const int*   items = (const int*)d_in[6];
  const int DIM = 64;
  const int NU = in_sizes[0] / DIM;
  const int NI = in_sizes[1] / DIM;
  const int E  = in_sizes[2];
  const int E2 = E / 2;             // first half: user rows, sorted by row
  const int B = in_sizes[5];
  const int NN = NU + NI;
  float* out = (float*)d_out;
  (void)n_in; (void)out_size; (void)ws_size;

  // derived subkeys: split(key(1234), 3) fold-like = threefry(key, (0, i))
  uint32_t ke0, ke1, ku0, ku1, ki0, ki1;
  tf2x32(0u, 1234u, 0u, 0u, ke0, ke1);
  tf2x32(0u, 1234u, 0u, 1u, ku0, ku1);
  tf2x32(0u, 1234u, 0u, 2u, ki0, ki1);

  // workspace carve
  char* p = (char*)d_ws;
  auto carve = [&](size_t bytes) {
    char* r = p;
    p += (bytes + 255) & ~(size_t)255;
    return (void*)r;
  };
  uint32_t* X0    = (uint32_t*)carve((size_t)NN * 32 * 4);  // bf16x2 rows
  uint32_t* X1    = (uint32_t*)carve((size_t)NN * 32 * 4);
  int2*  uslot    = (int2*)carve((size_t)E2 * 8);
  int2*  islot    = (int2*)carve((size_t)(E - E2) * 8);
  unsigned long long* keepw = (unsigned long long*)carve(((size_t)E / 64 + 2) * 8);
  int*   cnt      = (int*)carve((size_t)NI * 4);
  int*   row_ptr_u = (int*)carve((size_t)(NU + 1) * 4);
  int*   row_ptr_i = (int*)carve((size_t)(NI + 1) * 4);
  int*   nextc    = (int*)carve((size_t)NI * 4);
  uint8_t* fB     = (uint8_t*)carve((size_t)NN * 3);  // fB | f1 | f2
  uint8_t* f1     = fB + NN;
  uint8_t* f2     = fB + 2 * (size_t)NN;
  int*   list1    = (int*)carve((size_t)NN * 4);
  int*   list2    = (int*)carve((size_t)NN * 4);
  const int GK    = (E + 1023) / 1024;      // k_keep grid
  const int NBE   = (E2 + 1023) / 1024;     // first-half scan blocks
  const int NBI   = (NI + 255) / 256;       // item-count scan blocks
  const int NB    = (NN + 255) / 256;       // frontier scan blocks
  int*   bsumE    = (int*)carve((size_t)GK * 4);
  int*   bprefE   = (int*)carve((size_t)(NBE + 1) * 4);
  int*   bsumI    = (int*)carve((size_t)NBI * 4);
  int*   bprefI   = (int*)carve((size_t)(NBI + 1) * 4);
  int*   bsum1    = (int*)carve((size_t)NB * 4);
  int*   bpref1   = (int*)carve((size_t)(NB + 1) * 4);   // bpref1[NB] = |list1|
  int*   bsum2    = (int*)carve((size_t)NB * 4);
  int*   bpref2   = (int*)carve((size_t)(NB + 1) * 4);   // bpref2[NB] = |list2|

  hipMemsetAsync(cnt, 0, (size_t)NI * 4, stream);
  hipMemsetAsync(fB, 0, (size_t)NN * 3, stream);

  // CSR build: deterministic coalesced compaction (user half, row-sorted) +
  // small atomic scatter (item half)
  k_keep<<<GK, 1024, 0, stream>>>(rows, E, E2, NU, keepw, bsumE, cnt, ke0, ke1);
  k_blocksum<<<NBI, 256, 0, stream>>>(cnt, NI, bsumI);
  k_scanb2x<<<1, 1024, 0, stream>>>(bsumE, NBE, bprefE, bsumI, NBI, bprefI);
  k_scan_write<<<NBI, 256, 0, stream>>>(cnt, NI, bprefI, row_ptr_i, nextc);
  k_compactU<<<NBE, 1024, 0, stream>>>(rows, cols, avals, keepw, bprefE, E2, NU, NBE,
                                       uslot, row_ptr_u);
  {
    const int gI = (E - E2 + 255) / 256;
    k_scatterI<<<gI, 256, 0, stream>>>(rows, cols, avals, keepw, E, E2, NU, nextc, islot);
  }

  // frontier: f2 = batch ∪ N(batch); f1 = batch ∪ N(f2); scan-compact to lists
  const int gB = (2 * B + 255) / 256;
  const int gN = (NN + 255) / 256;
  k_mark_batch<<<gB, 256, 0, stream>>>(users, items, B, NU, fB, f1, f2);
  k_mark_neighbors<<<gN, 256, 0, stream>>>(fB, row_ptr_u, uslot, row_ptr_i, islot, NN, NU, f2);
  k_mark_neighbors<<<gN, 256, 0, stream>>>(f2, row_ptr_u, uslot, row_ptr_i, islot, NN, NU, f1);
  k_flagsum2<<<NB, 256, 0, stream>>>(f1, f2, NN, bsum1, bsum2);
  k_scanb2x<<<1, 1024, 0, stream>>>(bsum1, NB, bpref1, bsum2, NB, bpref2);
  k_compact2<<<NB, 256, 0, stream>>>(f1, f2, NN, bpref1, bpref2, list1, list2);

  const int gG = (2 * B + 31) / 32;   // 32 batch slots/block (8 lanes each)
  const int gS = (NN + 31) / 32;      // upper bound; spmm exits past nrows

  // layer 1: X0 = A * emb (rows in f1)
  k_spmm<1><<<gS, 256, 0, stream>>>(row_ptr_u, uslot, row_ptr_i, islot, X1,
                                    uemb, iemb, X0, list1, bpref1 + NB, NU);
  // out_online = emb + X0 at batch rows (pure write)
  k_gatherA<<<gG, 256, 0, stream>>>(X0, uemb, iemb, users, items, out, B, NU);
  // layer 2: X1 = A * X0 (rows in f2)
  k_spmm<0><<<gS, 256, 0, stream>>>(row_ptr_u, uslot, row_ptr_i, islot, X0,
                                    uemb, iemb, X1, list2, bpref2 + NB, NU);
  // tail: += X1 (layer 2) + A*X1 (layer 3), /4, target masks — one RMW pass
  k_tail<<<gG, 256, 0, stream>>>(row_ptr_u, uslot, row_ptr_i, islot, X1,
                                 users, items, out, B, NU, ku0, ku1, ki0, ki1);
}